// Round 11
// baseline (229.884 us; speedup 1.0000x reference)
//
#include <hip/hip_runtime.h>
#include <math.h>

#define H1 224
#define W1 224
#define H2 112
#define W2 112
#define HP 56
#define WP 56

#define NS 32
#define SLOT_STRIDE 64

// ---------------- complex helpers (quantum circuit) ----------------
struct C2 { float re, im; };
__device__ __forceinline__ C2 cmul(C2 a, C2 b) {
    return C2{fmaf(a.re, b.re, -a.im * b.im), fmaf(a.re, b.im, a.im * b.re)};
}
__device__ __forceinline__ C2 cadd(C2 a, C2 b) { return C2{a.re + b.re, a.im + b.im}; }

template <int S>
__device__ __forceinline__ void ap1s(C2* st, C2 u00, C2 u01, C2 u10, C2 u11) {
#pragma unroll
    for (int i = 0; i < 16; i++) {
        if (i & S) continue;
        C2 a0 = st[i], a1 = st[i + S];
        st[i]     = cadd(cmul(u00, a0), cmul(u01, a1));
        st[i + S] = cadd(cmul(u10, a0), cmul(u11, a1));
    }
}
template <int SC, int STT>
__device__ __forceinline__ void cnot_s(C2* st) {
#pragma unroll
    for (int i = 0; i < 16; i++)
        if ((i & SC) && !(i & STT)) { C2 t = st[i]; st[i] = st[i + STT]; st[i + STT] = t; }
}
struct M2 { C2 m[2][2]; };
__device__ __forceinline__ M2 mmul(const M2& A, const M2& B) {
    M2 R;
#pragma unroll
    for (int i = 0; i < 2; i++)
#pragma unroll
        for (int j = 0; j < 2; j++)
            R.m[i][j] = cadd(cmul(A.m[i][0], B.m[0][j]), cmul(A.m[i][1], B.m[1][j]));
    return R;
}
// combined U = Rx(p2) * Rz(p1) * Ry(p0)
__device__ __forceinline__ M2 combined_u(const float* __restrict__ p) {
    float c0 = cosf(0.5f * p[0]), s0 = sinf(0.5f * p[0]);
    float c1 = cosf(0.5f * p[1]), s1 = sinf(0.5f * p[1]);
    float c2 = cosf(0.5f * p[2]), s2 = sinf(0.5f * p[2]);
    M2 Ry = {{{{c0, 0.f}, {-s0, 0.f}}, {{s0, 0.f}, {c0, 0.f}}}};
    M2 Rz = {{{{c1, -s1}, {0.f, 0.f}}, {{0.f, 0.f}, {c1, s1}}}};
    M2 Rx = {{{{c2, 0.f}, {0.f, -s2}}, {{0.f, -s2}, {c2, 0.f}}}};
    return mmul(Rx, mmul(Rz, Ry));
}

// ---------------- multi-row LDS tree reduction (256 threads, Q rows) ----------------
template <int Q>
__device__ __forceinline__ void rows_reduce(float* red, const float* vals, int tid) {
#pragma unroll
    for (int q = 0; q < Q; q++) red[q * 256 + tid] = vals[q];
    __syncthreads();
    for (int s = 128; s > 0; s >>= 1) {
        for (int idx = tid; idx < Q * s; idx += 256) {
            int row = idx / s, i = idx - row * s;
            red[row * 256 + i] += red[row * 256 + i + s];
        }
        __syncthreads();
    }
}

__global__ void zero_ws(float* ws, int n) {
    int i = blockIdx.x * blockDim.x + threadIdx.x;
    if (i < n) ws[i] = 0.f;
}

__device__ __forceinline__ float slot_sum(const float* stats, int c) {
    float s = 0.f;
#pragma unroll
    for (int sl = 0; sl < NS; sl++) s += stats[sl * SLOT_STRIDE + c];
    return s;
}

// ---------------- K1a (tier A): conv1 stats + pooled-extreme store ----------------
// grid (7,B) x 256; thread = column, 32-row strip; pooled extreme per sign(g1[c]).
__global__ void conv1_pool_stats(const float* __restrict__ x, const float* __restrict__ w,
                                 const float* __restrict__ bias, const float* __restrict__ g1,
                                 float* __restrict__ stats, float* __restrict__ p1ext) {
    __shared__ float red[16 * 256];
    int strip = blockIdx.x;
    int b = blockIdx.y;
    int tid = threadIdx.x;
    const float* xb = x + (size_t)b * H1 * W1;
    float sums[8], sqs[8], pm[8];
    bool gp[8];
#pragma unroll
    for (int c = 0; c < 8; c++) { sums[c] = 0.f; sqs[c] = 0.f; gp[c] = g1[c] >= 0.f; }
    int col = tid;
    if (col < W1) {
        bool cl = col > 0, cr = col < W1 - 1;
        int row0 = strip * 32;
        float a0, a1, a2, b0, b1, b2, c0, c1, c2;
        {
            int r = row0 - 1;
            if (r >= 0) {
                a0 = cl ? xb[r * W1 + col - 1] : 0.f;
                a1 = xb[r * W1 + col];
                a2 = cr ? xb[r * W1 + col + 1] : 0.f;
            } else { a0 = a1 = a2 = 0.f; }
            r = row0;
            b0 = cl ? xb[r * W1 + col - 1] : 0.f;
            b1 = xb[r * W1 + col];
            b2 = cr ? xb[r * W1 + col + 1] : 0.f;
        }
        for (int rr = 0; rr < 32; rr++) {
            int rn = row0 + rr + 1;
            if (rn < H1) {
                c0 = cl ? xb[rn * W1 + col - 1] : 0.f;
                c1 = xb[rn * W1 + col];
                c2 = cr ? xb[rn * W1 + col + 1] : 0.f;
            } else { c0 = c1 = c2 = 0.f; }
#pragma unroll
            for (int c = 0; c < 8; c++) {
                float acc = bias[c];
                acc = fmaf(w[c * 9 + 0], a0, acc);
                acc = fmaf(w[c * 9 + 1], a1, acc);
                acc = fmaf(w[c * 9 + 2], a2, acc);
                acc = fmaf(w[c * 9 + 3], b0, acc);
                acc = fmaf(w[c * 9 + 4], b1, acc);
                acc = fmaf(w[c * 9 + 5], b2, acc);
                acc = fmaf(w[c * 9 + 6], c0, acc);
                acc = fmaf(w[c * 9 + 7], c1, acc);
                acc = fmaf(w[c * 9 + 8], c2, acc);
                sums[c] += acc;
                sqs[c] = fmaf(acc, acc, sqs[c]);
                if ((rr & 1) == 0) {
                    pm[c] = acc;
                } else {
                    float m = gp[c] ? fmaxf(pm[c], acc) : fminf(pm[c], acc);
                    float mo = __shfl_xor(m, 1, 64);
                    m = gp[c] ? fmaxf(m, mo) : fminf(m, mo);
                    if ((tid & 1) == 0) {
                        int prow = strip * 16 + (rr >> 1);
                        p1ext[(((size_t)b * 8 + c) * H2 + prow) * W2 + (col >> 1)] = m;
                    }
                }
            }
            a0 = b0; a1 = b1; a2 = b2;
            b0 = c0; b1 = c1; b2 = c2;
        }
    }
    float vals[16];
#pragma unroll
    for (int c = 0; c < 8; c++) { vals[c] = sums[c]; vals[8 + c] = sqs[c]; }
    rows_reduce<16>(red, vals, tid);
    int slot = (b * 7 + strip) & (NS - 1);
    if (tid < 16) atomicAdd(stats + slot * SLOT_STRIDE + tid, red[tid * 256]);
}

// ---------------- K1b (tier B/C): conv1 stats only ----------------
__global__ void conv1_stats(const float* __restrict__ x, const float* __restrict__ w,
                            const float* __restrict__ bias, float* __restrict__ stats) {
    __shared__ float red[16 * 256];
    int strip = blockIdx.x;
    int b = blockIdx.y;
    int tid = threadIdx.x;
    const float* xb = x + (size_t)b * H1 * W1;
    float sums[8], sqs[8];
#pragma unroll
    for (int c = 0; c < 8; c++) { sums[c] = 0.f; sqs[c] = 0.f; }
    int col = tid;
    if (col < W1) {
        bool cl = col > 0, cr = col < W1 - 1;
        int row0 = strip * 32;
        float a0, a1, a2, b0, b1, b2, c0, c1, c2;
        {
            int r = row0 - 1;
            if (r >= 0) {
                a0 = cl ? xb[r * W1 + col - 1] : 0.f;
                a1 = xb[r * W1 + col];
                a2 = cr ? xb[r * W1 + col + 1] : 0.f;
            } else { a0 = a1 = a2 = 0.f; }
            r = row0;
            b0 = cl ? xb[r * W1 + col - 1] : 0.f;
            b1 = xb[r * W1 + col];
            b2 = cr ? xb[r * W1 + col + 1] : 0.f;
        }
        for (int rr = 0; rr < 32; rr++) {
            int rn = row0 + rr + 1;
            if (rn < H1) {
                c0 = cl ? xb[rn * W1 + col - 1] : 0.f;
                c1 = xb[rn * W1 + col];
                c2 = cr ? xb[rn * W1 + col + 1] : 0.f;
            } else { c0 = c1 = c2 = 0.f; }
#pragma unroll
            for (int c = 0; c < 8; c++) {
                float acc = bias[c];
                acc = fmaf(w[c * 9 + 0], a0, acc);
                acc = fmaf(w[c * 9 + 1], a1, acc);
                acc = fmaf(w[c * 9 + 2], a2, acc);
                acc = fmaf(w[c * 9 + 3], b0, acc);
                acc = fmaf(w[c * 9 + 4], b1, acc);
                acc = fmaf(w[c * 9 + 5], b2, acc);
                acc = fmaf(w[c * 9 + 6], c0, acc);
                acc = fmaf(w[c * 9 + 7], c1, acc);
                acc = fmaf(w[c * 9 + 8], c2, acc);
                sums[c] += acc;
                sqs[c] = fmaf(acc, acc, sqs[c]);
            }
            a0 = b0; a1 = b1; a2 = b2;
            b0 = c0; b1 = c1; b2 = c2;
        }
    }
    float vals[16];
#pragma unroll
    for (int c = 0; c < 8; c++) { vals[c] = sums[c]; vals[8 + c] = sqs[c]; }
    rows_reduce<16>(red, vals, tid);
    int slot = (b * 7 + strip) & (NS - 1);
    if (tid < 16) atomicAdd(stats + slot * SLOT_STRIDE + tid, red[tid * 256]);
}

// build h1 tile by conv1 recompute (tier B/C)
template <int PH, int PW>
__device__ __forceinline__ void build_h1_tile(const float* __restrict__ xb,
                                              float (*h1t)[PH][PW],
                                              const float* __restrict__ w1,
                                              const float* __restrict__ b1,
                                              const float* sc1, const float* sh1,
                                              int oy0, int ox0, int tid) {
    for (int i = tid; i < PH * PW; i += 256) {
        int p = i / PW, q = i % PW;
        int hy = oy0 + p, hx = ox0 + q;
        bool ok = (hy >= 0 && hy < H2 && hx >= 0 && hx < W2);
        float xp[5][5];
        if (hy >= 1 && hy <= H2 - 2 && hx >= 1 && hx <= W2 - 2) {
            const float* bp = xb + (2 * hy - 1) * W1 + (2 * hx - 1);
#pragma unroll
            for (int r = 0; r < 5; r++)
#pragma unroll
                for (int c = 0; c < 5; c++) xp[r][c] = bp[r * W1 + c];
        } else if (ok) {
#pragma unroll
            for (int r = 0; r < 5; r++)
#pragma unroll
                for (int c = 0; c < 5; c++) {
                    int gy = 2 * hy - 1 + r, gx = 2 * hx - 1 + c;
                    xp[r][c] = (gy >= 0 && gy < H1 && gx >= 0 && gx < W1) ? xb[gy * W1 + gx] : 0.f;
                }
        }
#pragma unroll
        for (int c = 0; c < 8; c++) {
            float mx = 0.f;
            if (ok) {
                mx = -INFINITY;
#pragma unroll
                for (int dy = 0; dy < 2; dy++)
#pragma unroll
                    for (int dx = 0; dx < 2; dx++) {
                        float acc = b1[c];
#pragma unroll
                        for (int ky = 0; ky < 3; ky++)
#pragma unroll
                            for (int kx = 0; kx < 3; kx++)
                                acc = fmaf(w1[c * 9 + ky * 3 + kx], xp[dy + ky][dx + kx], acc);
                        mx = fmaxf(mx, fmaxf(fmaf(acc, sc1[c], sh1[c]), 0.f));
                    }
            }
            h1t[c][p][q] = mx;
        }
    }
}

// ---------------- K2a (tier A): conv2 stats from p1ext, 28x28 tile, pooled ext store ----------------
__global__ __launch_bounds__(256, 4) void conv2_stats_slim(
        const float* __restrict__ p1ext, const float* __restrict__ g1,
        const float* __restrict__ be1, const float* __restrict__ stats1,
        const float* __restrict__ w2, const float* __restrict__ b2,
        const float* __restrict__ g2,
        float* __restrict__ stats2, float* __restrict__ p2ext, float N1) {
    __shared__ __align__(16) float h1t[8][30][30];
    __shared__ float sc1[8], sh1[8];
    int b = blockIdx.z;
    int Y0 = blockIdx.y * 28, X0 = blockIdx.x * 28;
    int ty = threadIdx.y, tx = threadIdx.x;
    int tid = ty * 16 + tx;
    if (tid < 8) {
        float su = slot_sum(stats1, tid), sq = slot_sum(stats1, 8 + tid);
        float mu = su / N1;
        float var = sq / N1 - mu * mu;
        float sc = g1[tid] * rsqrtf(var + 1e-5f);
        sc1[tid] = sc;
        sh1[tid] = be1[tid] - mu * sc;
    }
    __syncthreads();
    const float* pb = p1ext + (size_t)b * 8 * H2 * W2;
    for (int i = tid; i < 8 * 30 * 30; i += 256) {
        int c = i / 900, r = (i % 900) / 30, q = i % 30;
        int hy = Y0 - 1 + r, hx = X0 - 1 + q;
        float v = 0.f;
        if (hy >= 0 && hy < H2 && hx >= 0 && hx < W2) {
            float e = pb[c * H2 * W2 + hy * W2 + hx];
            v = fmaxf(fmaf(e, sc1[c], sh1[c]), 0.f);
        }
        h1t[c][r][q] = v;
    }
    __syncthreads();
    bool act = (ty < 14) && (tx < 14);
    float acc[4][2][2];
#pragma unroll
    for (int co = 0; co < 4; co++)
#pragma unroll
        for (int dy = 0; dy < 2; dy++)
#pragma unroll
            for (int dx = 0; dx < 2; dx++) acc[co][dy][dx] = b2[co];
    if (act) {
#pragma unroll
        for (int ci = 0; ci < 8; ci++) {
            float win[4][4];
#pragma unroll
            for (int r = 0; r < 4; r++) {
                const float2* rp = (const float2*)&h1t[ci][2 * ty + r][2 * tx];
                float2 u = rp[0], v = rp[1];
                win[r][0] = u.x; win[r][1] = u.y; win[r][2] = v.x; win[r][3] = v.y;
            }
#pragma unroll
            for (int co = 0; co < 4; co++)
#pragma unroll
                for (int ky = 0; ky < 3; ky++)
#pragma unroll
                    for (int kx = 0; kx < 3; kx++) {
                        float wv = w2[co * 72 + ci * 9 + ky * 3 + kx];
#pragma unroll
                        for (int dy = 0; dy < 2; dy++)
#pragma unroll
                            for (int dx = 0; dx < 2; dx++)
                                acc[co][dy][dx] = fmaf(wv, win[dy + ky][dx + kx], acc[co][dy][dx]);
                    }
        }
    }
    float vals[8];
#pragma unroll
    for (int co = 0; co < 4; co++) {
        float s = acc[co][0][0] + acc[co][0][1] + acc[co][1][0] + acc[co][1][1];
        float q = acc[co][0][0] * acc[co][0][0] + acc[co][0][1] * acc[co][0][1] +
                  acc[co][1][0] * acc[co][1][0] + acc[co][1][1] * acc[co][1][1];
        vals[co] = act ? s : 0.f;
        vals[4 + co] = act ? q : 0.f;
    }
    if (act) {
        int hy = (Y0 >> 1) + ty, hx = (X0 >> 1) + tx;  // in [0,56)
#pragma unroll
        for (int co = 0; co < 4; co++) {
            float mx = fmaxf(fmaxf(acc[co][0][0], acc[co][0][1]),
                             fmaxf(acc[co][1][0], acc[co][1][1]));
            float mn = fminf(fminf(acc[co][0][0], acc[co][0][1]),
                             fminf(acc[co][1][0], acc[co][1][1]));
            p2ext[(((size_t)b * 4 + co) * HP + hy) * WP + hx] = (g2[co] >= 0.f) ? mx : mn;
        }
    }
    __syncthreads();
    float* red = (float*)h1t;  // 2048 <= 7200 floats
    rows_reduce<8>(red, vals, tid);
    int slot = ((b * 16) + blockIdx.y * 4 + blockIdx.x) & (NS - 1);
    if (tid < 8) atomicAdd(stats2 + slot * SLOT_STRIDE + tid, red[tid * 256]);
}

// ---------------- K2b (tier B/C): conv2 stats with conv1 recompute ----------------
template <bool STORE>
__global__ __launch_bounds__(256, 4) void conv2_stats_fused(
        const float* __restrict__ x, const float* __restrict__ w1,
        const float* __restrict__ b1, const float* __restrict__ g1,
        const float* __restrict__ be1, const float* __restrict__ stats1,
        const float* __restrict__ w2, const float* __restrict__ b2,
        float* __restrict__ stats2,
        float* __restrict__ pmax, float* __restrict__ pmin, float N1) {
    __shared__ __align__(16) float h1t[8][34][34];
    __shared__ float sc1[8], sh1[8];
    int b = blockIdx.z;
    int Y0 = blockIdx.y * 32, X0 = blockIdx.x * 32;
    int ty = threadIdx.y, tx = threadIdx.x;
    int tid = ty * 16 + tx;
    if (tid < 8) {
        float su = slot_sum(stats1, tid), sq = slot_sum(stats1, 8 + tid);
        float mu = su / N1;
        float var = sq / N1 - mu * mu;
        float sc = g1[tid] * rsqrtf(var + 1e-5f);
        sc1[tid] = sc;
        sh1[tid] = be1[tid] - mu * sc;
    }
    __syncthreads();
    const float* xb = x + (size_t)b * H1 * W1;
    build_h1_tile<34, 34>(xb, h1t, w1, b1, sc1, sh1, Y0 - 1, X0 - 1, tid);
    __syncthreads();
    float acc[4][2][2];
#pragma unroll
    for (int co = 0; co < 4; co++)
#pragma unroll
        for (int dy = 0; dy < 2; dy++)
#pragma unroll
            for (int dx = 0; dx < 2; dx++) acc[co][dy][dx] = b2[co];
#pragma unroll
    for (int ci = 0; ci < 8; ci++) {
        float win[4][4];
#pragma unroll
        for (int r = 0; r < 4; r++) {
            const float2* rp = (const float2*)&h1t[ci][2 * ty + r][2 * tx];
            float2 u = rp[0], v = rp[1];
            win[r][0] = u.x; win[r][1] = u.y; win[r][2] = v.x; win[r][3] = v.y;
        }
#pragma unroll
        for (int co = 0; co < 4; co++)
#pragma unroll
            for (int ky = 0; ky < 3; ky++)
#pragma unroll
                for (int kx = 0; kx < 3; kx++) {
                    float wv = w2[co * 72 + ci * 9 + ky * 3 + kx];
#pragma unroll
                    for (int dy = 0; dy < 2; dy++)
#pragma unroll
                        for (int dx = 0; dx < 2; dx++)
                            acc[co][dy][dx] = fmaf(wv, win[dy + ky][dx + kx], acc[co][dy][dx]);
                }
    }
    int cy0 = Y0 + 2 * ty, cx0 = X0 + 2 * tx;
    bool vy0 = cy0 < H2, vy1 = cy0 + 1 < H2, vx0 = cx0 < W2, vx1 = cx0 + 1 < W2;
    float vals[8];
#pragma unroll
    for (int co = 0; co < 4; co++) {
        float s = 0.f, q = 0.f;
        if (vy0 && vx0) { float a = acc[co][0][0]; s += a; q = fmaf(a, a, q); }
        if (vy0 && vx1) { float a = acc[co][0][1]; s += a; q = fmaf(a, a, q); }
        if (vy1 && vx0) { float a = acc[co][1][0]; s += a; q = fmaf(a, a, q); }
        if (vy1 && vx1) { float a = acc[co][1][1]; s += a; q = fmaf(a, a, q); }
        vals[co] = s;
        vals[4 + co] = q;
    }
    if (STORE) {
        int hy = (Y0 >> 1) + ty, hx = (X0 >> 1) + tx;
        if (hy < HP && hx < WP) {
#pragma unroll
            for (int co = 0; co < 4; co++) {
                float mx = fmaxf(fmaxf(acc[co][0][0], acc[co][0][1]),
                                 fmaxf(acc[co][1][0], acc[co][1][1]));
                float mn = fminf(fminf(acc[co][0][0], acc[co][0][1]),
                                 fminf(acc[co][1][0], acc[co][1][1]));
                size_t idx = (((size_t)b * 4 + co) * HP + hy) * WP + hx;
                pmax[idx] = mx;
                pmin[idx] = mn;
            }
        }
    }
    __syncthreads();
    float* red = (float*)h1t;
    rows_reduce<8>(red, vals, tid);
    int slot = ((b * 16) + blockIdx.y * 4 + blockIdx.x) & (NS - 1);
    if (tid < 8) atomicAdd(stats2 + slot * SLOT_STRIDE + tid, red[tid * 256]);
}

// ---------------- K3: BN2+relu on pooled extrema + spatial mean + f-stat atomics ----------------
// grid B*4 blocks; for tier A pass (p2ext, p2ext).
__global__ void pool_bn_mean(const float* __restrict__ pmax, const float* __restrict__ pmin,
                             const float* __restrict__ g2, const float* __restrict__ be2,
                             const float* __restrict__ stats2,
                             float* __restrict__ featbuf, float* __restrict__ gstats, float N2) {
    __shared__ float red[256];
    int co = blockIdx.x & 3;
    int b = blockIdx.x >> 2;
    int tid = threadIdx.x;
    float su = slot_sum(stats2, co), sq = slot_sum(stats2, 4 + co);
    float mu = su / N2;
    float var = sq / N2 - mu * mu;
    float sc = g2[co] * rsqrtf(var + 1e-5f);
    float sh = be2[co] - mu * sc;
    const float* P = (sc >= 0.f ? pmax : pmin) + ((size_t)b * 4 + co) * (HP * WP);
    float s = 0.f;
    for (int i = tid; i < HP * WP; i += 256) s += fmaxf(fmaf(P[i], sc, sh), 0.f);
    red[tid] = s;
    __syncthreads();
    for (int st = 128; st > 0; st >>= 1) {
        if (tid < st) red[tid] += red[tid + st];
        __syncthreads();
    }
    if (tid == 0) {
        featbuf[(size_t)b * 4 + co] = red[0];
        float f = red[0] * (1.f / (HP * WP));
        atomicAdd(gstats + 0, f);
        atomicAdd(gstats + 1, f * f);
    }
}

// ---------------- K3c (tier C): conv2 recompute + BN2 + pool + spatial sum ----------------
__global__ void conv2_final_fused(const float* __restrict__ x, const float* __restrict__ w1,
                                  const float* __restrict__ b1, const float* __restrict__ g1,
                                  const float* __restrict__ be1,
                                  const float* __restrict__ stats1,
                                  const float* __restrict__ w2, const float* __restrict__ b2,
                                  const float* __restrict__ g2, const float* __restrict__ be2,
                                  const float* __restrict__ stats2,
                                  float* __restrict__ featbuf, float N1, float N2) {
    __shared__ __align__(16) float h1t[8][34][34];
    __shared__ float sc1[8], sh1[8];
    __shared__ float sc2[4], sh2[4];
    int b = blockIdx.z;
    int py0 = blockIdx.y * 16, px0 = blockIdx.x * 16;
    int ty = threadIdx.y, tx = threadIdx.x;
    int tid = ty * 16 + tx;
    if (tid < 8) {
        float su = slot_sum(stats1, tid), sq = slot_sum(stats1, 8 + tid);
        float mu = su / N1;
        float var = sq / N1 - mu * mu;
        float sc = g1[tid] * rsqrtf(var + 1e-5f);
        sc1[tid] = sc;
        sh1[tid] = be1[tid] - mu * sc;
    }
    if (tid >= 16 && tid < 20) {
        int j = tid - 16;
        float su = slot_sum(stats2, j), sq = slot_sum(stats2, 4 + j);
        float mu = su / N2;
        float var = sq / N2 - mu * mu;
        float sc = g2[j] * rsqrtf(var + 1e-5f);
        sc2[j] = sc;
        sh2[j] = be2[j] - mu * sc;
    }
    __syncthreads();
    const float* xb = x + (size_t)b * H1 * W1;
    build_h1_tile<34, 34>(xb, h1t, w1, b1, sc1, sh1, 2 * py0 - 1, 2 * px0 - 1, tid);
    __syncthreads();
    bool valid = (py0 + ty < HP) && (px0 + tx < WP);
    float acc[4][2][2];
#pragma unroll
    for (int co = 0; co < 4; co++)
#pragma unroll
        for (int dy = 0; dy < 2; dy++)
#pragma unroll
            for (int dx = 0; dx < 2; dx++) acc[co][dy][dx] = b2[co];
#pragma unroll
    for (int ci = 0; ci < 8; ci++) {
        float win[4][4];
#pragma unroll
        for (int r = 0; r < 4; r++) {
            const float2* rp = (const float2*)&h1t[ci][2 * ty + r][2 * tx];
            float2 u = rp[0], v = rp[1];
            win[r][0] = u.x; win[r][1] = u.y; win[r][2] = v.x; win[r][3] = v.y;
        }
#pragma unroll
        for (int co = 0; co < 4; co++)
#pragma unroll
            for (int ky = 0; ky < 3; ky++)
#pragma unroll
                for (int kx = 0; kx < 3; kx++) {
                    float wv = w2[co * 72 + ci * 9 + ky * 3 + kx];
#pragma unroll
                    for (int dy = 0; dy < 2; dy++)
#pragma unroll
                        for (int dx = 0; dx < 2; dx++)
                            acc[co][dy][dx] = fmaf(wv, win[dy + ky][dx + kx], acc[co][dy][dx]);
                }
    }
    float vals[4];
#pragma unroll
    for (int co = 0; co < 4; co++) {
        float mx = -INFINITY;
#pragma unroll
        for (int dy = 0; dy < 2; dy++)
#pragma unroll
            for (int dx = 0; dx < 2; dx++)
                mx = fmaxf(mx, fmaxf(fmaf(acc[co][dy][dx], sc2[co], sh2[co]), 0.f));
        vals[co] = valid ? mx : 0.f;
    }
    __syncthreads();
    float* red = (float*)h1t;
    rows_reduce<4>(red, vals, tid);
    if (tid < 4) atomicAdd(featbuf + (size_t)b * 4 + tid, red[tid * 256]);
}

// ---------------- K4a: per-batch circuit (B blocks x 64; parallel I-fetch) ----------------
__global__ void circuit(const float* __restrict__ featbuf, const float* __restrict__ gstats,
                        const float* __restrict__ theta, const float* __restrict__ rho,
                        float* __restrict__ ebuf, float* __restrict__ gst_out, int B) {
    int b = blockIdx.x;
    float f[4];
#pragma unroll
    for (int j = 0; j < 4; j++) f[j] = featbuf[b * 4 + j] * (1.f / (HP * WP));
    float n = 4.f * (float)B;
    float mean = gstats[0] / n;
    float var1 = (gstats[1] - n * mean * mean) / (n - 1.f);
    float stdv = sqrtf(fmaxf(var1, 0.f)) + 1e-6f;
    const float PI = 3.14159265358979323846f;
    float cs[4], sn[4];
#pragma unroll
    for (int j = 0; j < 4; j++) {
        float sc = (f[j] - mean) / stdv * PI;
        cs[j] = cosf(0.5f * sc);
        sn[j] = sinf(0.5f * sc);
    }
    C2 st[16];
    {
        float amp[16];
        amp[1] = sn[3]; amp[0] = cs[3];
#pragma unroll
        for (int k = 0; k < 2; k++) { amp[k + 2] = amp[k] * sn[2]; amp[k] *= cs[2]; }
#pragma unroll
        for (int k = 0; k < 4; k++) { amp[k + 4] = amp[k] * sn[1]; amp[k] *= cs[1]; }
#pragma unroll
        for (int k = 0; k < 8; k++) { amp[k + 8] = amp[k] * sn[0]; amp[k] *= cs[0]; }
#pragma unroll
        for (int i = 0; i < 16; i++) st[i] = C2{amp[i], 0.f};
    }
#pragma clang loop unroll(disable)
    for (int l = 0; l < 2; l++) {
        const float* p = (l == 0) ? theta : rho;
#pragma clang loop unroll(disable)
        for (int i = 0; i < 4; i++) {
            M2 U = combined_u(p + i * 3);
            switch (i) {
            case 0: ap1s<8>(st, U.m[0][0], U.m[0][1], U.m[1][0], U.m[1][1]); break;
            case 1: ap1s<4>(st, U.m[0][0], U.m[0][1], U.m[1][0], U.m[1][1]); break;
            case 2: ap1s<2>(st, U.m[0][0], U.m[0][1], U.m[1][0], U.m[1][1]); break;
            default: ap1s<1>(st, U.m[0][0], U.m[0][1], U.m[1][0], U.m[1][1]); break;
            }
        }
        if (l == 0) { cnot_s<8, 4>(st); cnot_s<4, 2>(st); cnot_s<2, 1>(st); }
        else        { cnot_s<4, 8>(st); cnot_s<2, 4>(st); cnot_s<1, 2>(st); }
    }
    if (threadIdx.x == 0) {
#pragma unroll
        for (int qb = 0; qb < 4; qb++) {
            int m = 8 >> qb;
            float p0 = 0.f, p1 = 0.f;
#pragma unroll
            for (int i = 0; i < 16; i++) {
                float pr = st[i].re * st[i].re + st[i].im * st[i].im;
                if (i & m) p1 += pr; else p0 += pr;
            }
            float e = p0 - p1;
            ebuf[(size_t)b * 4 + qb] = e;
            atomicAdd(gst_out + 8 + qb, e);
            atomicAdd(gst_out + 12 + qb, e * e);
        }
    }
}

// ---------------- K4b: final batch-norm (tiny code, 1 block) ----------------
__global__ void bn_out(const float* __restrict__ ebuf, const float* __restrict__ gstats,
                       const float* __restrict__ ng, const float* __restrict__ nb,
                       float* __restrict__ out, int B) {
    int b = threadIdx.x;
#pragma clang loop unroll(disable)
    for (int j = 0; j < 4; j++) {
        float mu = gstats[8 + j] / (float)B;
        float v = gstats[12 + j] / (float)B - mu * mu;
        float e = ebuf[(size_t)b * 4 + j];
        out[b * 4 + j] = fmaf(e - mu, rsqrtf(fmaxf(v, 0.f) + 1e-5f) * ng[j], nb[j]);
    }
}

// ---------------- tier C monolithic finalize (kept for smallest-ws fallback) ----------------
__device__ __forceinline__ float bsum(float v, float* lds) {
#pragma unroll
    for (int off = 32; off; off >>= 1) v += __shfl_xor(v, off, 64);
    __syncthreads();
    if ((threadIdx.x & 63) == 0) lds[threadIdx.x >> 6] = v;
    __syncthreads();
    float r = 0.f;
    int nw = (int)(blockDim.x + 63) >> 6;
#pragma clang loop unroll(disable)
    for (int i = 0; i < nw; i++) r += lds[i];
    return r;
}

__global__ void finalize(const float* __restrict__ featbuf, const float* __restrict__ theta,
                         const float* __restrict__ rho, const float* __restrict__ ng,
                         const float* __restrict__ nb, float* __restrict__ out, int B) {
    __shared__ float lds[16];
    int b = threadIdx.x;
    float f[4];
#pragma unroll
    for (int j = 0; j < 4; j++) f[j] = featbuf[b * 4 + j] * (1.f / (HP * WP));
    float n = 4.f * (float)B;
    float mean = bsum(f[0] + f[1] + f[2] + f[3], lds) / n;
    float d2 = 0.f;
#pragma unroll
    for (int j = 0; j < 4; j++) { float d = f[j] - mean; d2 += d * d; }
    float var1 = bsum(d2, lds) / (n - 1.f);
    float stdv = sqrtf(fmaxf(var1, 0.f)) + 1e-6f;
    const float PI = 3.14159265358979323846f;
    float cs[4], sn[4];
#pragma unroll
    for (int j = 0; j < 4; j++) {
        float sc = (f[j] - mean) / stdv * PI;
        cs[j] = cosf(0.5f * sc);
        sn[j] = sinf(0.5f * sc);
    }
    C2 st[16];
    {
        float amp[16];
        amp[1] = sn[3]; amp[0] = cs[3];
#pragma unroll
        for (int k = 0; k < 2; k++) { amp[k + 2] = amp[k] * sn[2]; amp[k] *= cs[2]; }
#pragma unroll
        for (int k = 0; k < 4; k++) { amp[k + 4] = amp[k] * sn[1]; amp[k] *= cs[1]; }
#pragma unroll
        for (int k = 0; k < 8; k++) { amp[k + 8] = amp[k] * sn[0]; amp[k] *= cs[0]; }
#pragma unroll
        for (int i = 0; i < 16; i++) st[i] = C2{amp[i], 0.f};
    }
#pragma clang loop unroll(disable)
    for (int l = 0; l < 2; l++) {
        const float* p = (l == 0) ? theta : rho;
#pragma clang loop unroll(disable)
        for (int i = 0; i < 4; i++) {
            M2 U = combined_u(p + i * 3);
            switch (i) {
            case 0: ap1s<8>(st, U.m[0][0], U.m[0][1], U.m[1][0], U.m[1][1]); break;
            case 1: ap1s<4>(st, U.m[0][0], U.m[0][1], U.m[1][0], U.m[1][1]); break;
            case 2: ap1s<2>(st, U.m[0][0], U.m[0][1], U.m[1][0], U.m[1][1]); break;
            default: ap1s<1>(st, U.m[0][0], U.m[0][1], U.m[1][0], U.m[1][1]); break;
            }
        }
        if (l == 0) { cnot_s<8, 4>(st); cnot_s<4, 2>(st); cnot_s<2, 1>(st); }
        else        { cnot_s<4, 8>(st); cnot_s<2, 4>(st); cnot_s<1, 2>(st); }
    }
    float e[4];
#pragma unroll
    for (int qb = 0; qb < 4; qb++) {
        int m = 8 >> qb;
        float p0 = 0.f, p1 = 0.f;
#pragma unroll
        for (int i = 0; i < 16; i++) {
            float pr = st[i].re * st[i].re + st[i].im * st[i].im;
            if (i & m) p1 += pr; else p0 += pr;
        }
        e[qb] = p0 - p1;
    }
#pragma clang loop unroll(disable)
    for (int j = 0; j < 4; j++) {
        float mu = bsum(e[j], lds) / (float)B;
        float dv = e[j] - mu;
        float v = bsum(dv * dv, lds) / (float)B;
        out[b * 4 + j] = fmaf(dv, rsqrtf(v + 1e-5f) * ng[j], nb[j]);
    }
}

extern "C" void kernel_launch(void* const* d_in, const int* in_sizes, int n_in,
                              void* d_out, int out_size, void* d_ws, size_t ws_size,
                              hipStream_t stream) {
    const float* x     = (const float*)d_in[0];
    const float* w1    = (const float*)d_in[1];
    const float* b1    = (const float*)d_in[2];
    const float* g1    = (const float*)d_in[3];
    const float* be1   = (const float*)d_in[4];
    const float* w2    = (const float*)d_in[5];
    const float* b2    = (const float*)d_in[6];
    const float* g2    = (const float*)d_in[7];
    const float* be2   = (const float*)d_in[8];
    const float* theta = (const float*)d_in[9];
    const float* rho   = (const float*)d_in[10];
    const float* ng    = (const float*)d_in[11];
    const float* nb    = (const float*)d_in[12];
    float* out = (float*)d_out;

    int B = in_sizes[0] / (H1 * W1);

    float* ws = (float*)d_ws;
    float* stats1 = ws;                               // NS*64
    float* stats2 = ws + NS * SLOT_STRIDE;            // NS*64
    float* gstats = ws + 2 * NS * SLOT_STRIDE;        // 64: [0]=fsum,[1]=fsq,[8..11]=esum,[12..15]=esq
    float* featbuf = gstats + 64;                     // B*4
    float* ebuf = featbuf + (size_t)B * 4;            // B*4
    float* bufs = ebuf + (size_t)B * 4;

    size_t common = (size_t)(2 * NS * SLOT_STRIDE + 64) + (size_t)B * 8;
    size_t p2n = (size_t)B * 4 * HP * WP;             // pooled conv2 ext
    size_t p1n = (size_t)B * 8 * H2 * W2;             // pooled conv1 ext
    size_t needA = (common + p2n + p1n) * sizeof(float);
    size_t needB = (common + 2 * p2n) * sizeof(float);
    bool tierA = ws_size >= needA;                    // constants per process -> graph-safe
    bool tierB = !tierA && ws_size >= needB;

    float N1 = (float)B * H1 * W1;
    float N2 = (float)B * H2 * W2;
    int nz = (int)common;

    zero_ws<<<(nz + 255) / 256, 256, 0, stream>>>(ws, nz);
    if (tierA) {
        float* p2ext = bufs;
        float* p1ext = bufs + p2n;
        conv1_pool_stats<<<dim3(7, B), 256, 0, stream>>>(x, w1, b1, g1, stats1, p1ext);
        conv2_stats_slim<<<dim3(4, 4, B), dim3(16, 16), 0, stream>>>(
            p1ext, g1, be1, stats1, w2, b2, g2, stats2, p2ext, N1);
        pool_bn_mean<<<B * 4, 256, 0, stream>>>(p2ext, p2ext, g2, be2, stats2, featbuf, gstats, N2);
        circuit<<<B, 64, 0, stream>>>(featbuf, gstats, theta, rho, ebuf, gstats, B);
        bn_out<<<1, B, 0, stream>>>(ebuf, gstats, ng, nb, out, B);
    } else if (tierB) {
        float* pmax = bufs;
        float* pmin = bufs + p2n;
        conv1_stats<<<dim3(7, B), 256, 0, stream>>>(x, w1, b1, stats1);
        conv2_stats_fused<true><<<dim3(4, 4, B), dim3(16, 16), 0, stream>>>(
            x, w1, b1, g1, be1, stats1, w2, b2, stats2, pmax, pmin, N1);
        pool_bn_mean<<<B * 4, 256, 0, stream>>>(pmax, pmin, g2, be2, stats2, featbuf, gstats, N2);
        circuit<<<B, 64, 0, stream>>>(featbuf, gstats, theta, rho, ebuf, gstats, B);
        bn_out<<<1, B, 0, stream>>>(ebuf, gstats, ng, nb, out, B);
    } else {
        conv1_stats<<<dim3(7, B), 256, 0, stream>>>(x, w1, b1, stats1);
        conv2_stats_fused<false><<<dim3(4, 4, B), dim3(16, 16), 0, stream>>>(
            x, w1, b1, g1, be1, stats1, w2, b2, stats2, nullptr, nullptr, N1);
        conv2_final_fused<<<dim3(4, 4, B), dim3(16, 16), 0, stream>>>(
            x, w1, b1, g1, be1, stats1, w2, b2, g2, be2, stats2, featbuf, N1, N2);
        finalize<<<1, B, 0, stream>>>(featbuf, theta, rho, ng, nb, out, B);
    }
}

// Round 12
// 211.697 us; speedup vs baseline: 1.0859x; 1.0859x over previous
//
#include <hip/hip_runtime.h>
#include <math.h>

#define H1 224
#define W1 224
#define H2 112
#define W2 112
#define HP 56
#define WP 56

#define NS 32
#define SLOT_STRIDE 64

// ---------------- complex helpers (quantum circuit) ----------------
struct C2 { float re, im; };
__device__ __forceinline__ C2 cmul(C2 a, C2 b) {
    return C2{fmaf(a.re, b.re, -a.im * b.im), fmaf(a.re, b.im, a.im * b.re)};
}
__device__ __forceinline__ C2 cadd(C2 a, C2 b) { return C2{a.re + b.re, a.im + b.im}; }

template <int S>
__device__ __forceinline__ void ap1s(C2* st, C2 u00, C2 u01, C2 u10, C2 u11) {
#pragma unroll
    for (int i = 0; i < 16; i++) {
        if (i & S) continue;
        C2 a0 = st[i], a1 = st[i + S];
        st[i]     = cadd(cmul(u00, a0), cmul(u01, a1));
        st[i + S] = cadd(cmul(u10, a0), cmul(u11, a1));
    }
}
template <int SC, int STT>
__device__ __forceinline__ void cnot_s(C2* st) {
#pragma unroll
    for (int i = 0; i < 16; i++)
        if ((i & SC) && !(i & STT)) { C2 t = st[i]; st[i] = st[i + STT]; st[i + STT] = t; }
}
struct M2 { C2 m[2][2]; };
__device__ __forceinline__ M2 mmul(const M2& A, const M2& B) {
    M2 R;
#pragma unroll
    for (int i = 0; i < 2; i++)
#pragma unroll
        for (int j = 0; j < 2; j++)
            R.m[i][j] = cadd(cmul(A.m[i][0], B.m[0][j]), cmul(A.m[i][1], B.m[1][j]));
    return R;
}
// combined U = Rx(p2) * Rz(p1) * Ry(p0)
__device__ __forceinline__ M2 combined_u(const float* __restrict__ p) {
    float c0 = cosf(0.5f * p[0]), s0 = sinf(0.5f * p[0]);
    float c1 = cosf(0.5f * p[1]), s1 = sinf(0.5f * p[1]);
    float c2 = cosf(0.5f * p[2]), s2 = sinf(0.5f * p[2]);
    M2 Ry = {{{{c0, 0.f}, {-s0, 0.f}}, {{s0, 0.f}, {c0, 0.f}}}};
    M2 Rz = {{{{c1, -s1}, {0.f, 0.f}}, {{0.f, 0.f}, {c1, s1}}}};
    M2 Rx = {{{{c2, 0.f}, {0.f, -s2}}, {{0.f, -s2}, {c2, 0.f}}}};
    return mmul(Rx, mmul(Rz, Ry));
}

// ---------------- multi-row LDS tree reduction (256 threads, Q rows) ----------------
template <int Q>
__device__ __forceinline__ void rows_reduce(float* red, const float* vals, int tid) {
#pragma unroll
    for (int q = 0; q < Q; q++) red[q * 256 + tid] = vals[q];
    __syncthreads();
#pragma unroll
    for (int s = 128; s > 0; s >>= 1) {
        for (int idx = tid; idx < Q * s; idx += 256) {
            int row = idx / s, i = idx - row * s;
            red[row * 256 + i] += red[row * 256 + i + s];
        }
        __syncthreads();
    }
}

__global__ void zero_ws(float* ws, int n) {
    int i = blockIdx.x * blockDim.x + threadIdx.x;
    if (i < n) ws[i] = 0.f;
}

__device__ __forceinline__ float slot_sum(const float* stats, int c) {
    float s = 0.f;
#pragma unroll
    for (int sl = 0; sl < NS; sl++) s += stats[sl * SLOT_STRIDE + c];
    return s;
}

// ---------------- K1: conv1 batch stats; 16-row strips for latency hiding ----------------
// grid (14, B) x 256; thread = one column (224 active of 256).
__global__ void conv1_stats(const float* __restrict__ x, const float* __restrict__ w,
                            const float* __restrict__ bias, float* __restrict__ stats) {
    __shared__ float red[16 * 256];
    int strip = blockIdx.x;
    int b = blockIdx.y;
    int tid = threadIdx.x;
    const float* xb = x + (size_t)b * H1 * W1;
    float sums[8], sqs[8];
#pragma unroll
    for (int c = 0; c < 8; c++) { sums[c] = 0.f; sqs[c] = 0.f; }
    int col = tid;
    if (col < W1) {
        bool cl = col > 0, cr = col < W1 - 1;
        int row0 = strip * 16;
        float a0, a1, a2, b0, b1, b2, c0, c1, c2;
        {
            int r = row0 - 1;
            if (r >= 0) {
                a0 = cl ? xb[r * W1 + col - 1] : 0.f;
                a1 = xb[r * W1 + col];
                a2 = cr ? xb[r * W1 + col + 1] : 0.f;
            } else { a0 = a1 = a2 = 0.f; }
            r = row0;
            b0 = cl ? xb[r * W1 + col - 1] : 0.f;
            b1 = xb[r * W1 + col];
            b2 = cr ? xb[r * W1 + col + 1] : 0.f;
        }
        for (int rr = 0; rr < 16; rr++) {
            int rn = row0 + rr + 1;
            if (rn < H1) {
                c0 = cl ? xb[rn * W1 + col - 1] : 0.f;
                c1 = xb[rn * W1 + col];
                c2 = cr ? xb[rn * W1 + col + 1] : 0.f;
            } else { c0 = c1 = c2 = 0.f; }
#pragma unroll
            for (int c = 0; c < 8; c++) {
                float acc = bias[c];
                acc = fmaf(w[c * 9 + 0], a0, acc);
                acc = fmaf(w[c * 9 + 1], a1, acc);
                acc = fmaf(w[c * 9 + 2], a2, acc);
                acc = fmaf(w[c * 9 + 3], b0, acc);
                acc = fmaf(w[c * 9 + 4], b1, acc);
                acc = fmaf(w[c * 9 + 5], b2, acc);
                acc = fmaf(w[c * 9 + 6], c0, acc);
                acc = fmaf(w[c * 9 + 7], c1, acc);
                acc = fmaf(w[c * 9 + 8], c2, acc);
                sums[c] += acc;
                sqs[c] = fmaf(acc, acc, sqs[c]);
            }
            a0 = b0; a1 = b1; a2 = b2;
            b0 = c0; b1 = c1; b2 = c2;
        }
    }
    float vals[16];
#pragma unroll
    for (int c = 0; c < 8; c++) { vals[c] = sums[c]; vals[8 + c] = sqs[c]; }
    rows_reduce<16>(red, vals, tid);
    int slot = (b * 14 + strip) & (NS - 1);
    if (tid < 16) atomicAdd(stats + slot * SLOT_STRIDE + tid, red[tid * 256]);
}

// build h1 tile by conv1 recompute
template <int PH, int PW>
__device__ __forceinline__ void build_h1_tile(const float* __restrict__ xb,
                                              float (*h1t)[PH][PW],
                                              const float* __restrict__ w1,
                                              const float* __restrict__ b1,
                                              const float* sc1, const float* sh1,
                                              int oy0, int ox0, int tid) {
    for (int i = tid; i < PH * PW; i += 256) {
        int p = i / PW, q = i % PW;
        int hy = oy0 + p, hx = ox0 + q;
        bool ok = (hy >= 0 && hy < H2 && hx >= 0 && hx < W2);
        float xp[5][5];
        if (hy >= 1 && hy <= H2 - 2 && hx >= 1 && hx <= W2 - 2) {
            const float* bp = xb + (2 * hy - 1) * W1 + (2 * hx - 1);
#pragma unroll
            for (int r = 0; r < 5; r++)
#pragma unroll
                for (int c = 0; c < 5; c++) xp[r][c] = bp[r * W1 + c];
        } else if (ok) {
#pragma unroll
            for (int r = 0; r < 5; r++)
#pragma unroll
                for (int c = 0; c < 5; c++) {
                    int gy = 2 * hy - 1 + r, gx = 2 * hx - 1 + c;
                    xp[r][c] = (gy >= 0 && gy < H1 && gx >= 0 && gx < W1) ? xb[gy * W1 + gx] : 0.f;
                }
        }
#pragma unroll
        for (int c = 0; c < 8; c++) {
            float mx = 0.f;
            if (ok) {
                mx = -INFINITY;
#pragma unroll
                for (int dy = 0; dy < 2; dy++)
#pragma unroll
                    for (int dx = 0; dx < 2; dx++) {
                        float acc = b1[c];
#pragma unroll
                        for (int ky = 0; ky < 3; ky++)
#pragma unroll
                            for (int kx = 0; kx < 3; kx++)
                                acc = fmaf(w1[c * 9 + ky * 3 + kx], xp[dy + ky][dx + kx], acc);
                        mx = fmaxf(mx, fmaxf(fmaf(acc, sc1[c], sh1[c]), 0.f));
                    }
            }
            h1t[c][p][q] = mx;
        }
    }
}

// ---------------- K2: conv2 stats over a 32x32 tile; 2x2 quad (= pool cell)/thread ----------------
template <bool STORE>
__global__ __launch_bounds__(256, 4) void conv2_stats_fused(
        const float* __restrict__ x, const float* __restrict__ w1,
        const float* __restrict__ b1, const float* __restrict__ g1,
        const float* __restrict__ be1, const float* __restrict__ stats1,
        const float* __restrict__ w2, const float* __restrict__ b2,
        float* __restrict__ stats2,
        float* __restrict__ pmax, float* __restrict__ pmin, float N1) {
    __shared__ __align__(16) float h1t[8][34][34];
    __shared__ float sc1[8], sh1[8];
    int b = blockIdx.z;
    int Y0 = blockIdx.y * 32, X0 = blockIdx.x * 32;
    int ty = threadIdx.y, tx = threadIdx.x;
    int tid = ty * 16 + tx;
    if (tid < 8) {
        float su = slot_sum(stats1, tid), sq = slot_sum(stats1, 8 + tid);
        float mu = su / N1;
        float var = sq / N1 - mu * mu;
        float sc = g1[tid] * rsqrtf(var + 1e-5f);
        sc1[tid] = sc;
        sh1[tid] = be1[tid] - mu * sc;
    }
    __syncthreads();
    const float* xb = x + (size_t)b * H1 * W1;
    build_h1_tile<34, 34>(xb, h1t, w1, b1, sc1, sh1, Y0 - 1, X0 - 1, tid);
    __syncthreads();
    float acc[4][2][2];
#pragma unroll
    for (int co = 0; co < 4; co++)
#pragma unroll
        for (int dy = 0; dy < 2; dy++)
#pragma unroll
            for (int dx = 0; dx < 2; dx++) acc[co][dy][dx] = b2[co];
#pragma unroll
    for (int ci = 0; ci < 8; ci++) {
        float win[4][4];
#pragma unroll
        for (int r = 0; r < 4; r++) {
            const float2* rp = (const float2*)&h1t[ci][2 * ty + r][2 * tx];
            float2 u = rp[0], v = rp[1];
            win[r][0] = u.x; win[r][1] = u.y; win[r][2] = v.x; win[r][3] = v.y;
        }
#pragma unroll
        for (int co = 0; co < 4; co++)
#pragma unroll
            for (int ky = 0; ky < 3; ky++)
#pragma unroll
                for (int kx = 0; kx < 3; kx++) {
                    float wv = w2[co * 72 + ci * 9 + ky * 3 + kx];
#pragma unroll
                    for (int dy = 0; dy < 2; dy++)
#pragma unroll
                        for (int dx = 0; dx < 2; dx++)
                            acc[co][dy][dx] = fmaf(wv, win[dy + ky][dx + kx], acc[co][dy][dx]);
                }
    }
    int cy0 = Y0 + 2 * ty, cx0 = X0 + 2 * tx;
    bool vy0 = cy0 < H2, vy1 = cy0 + 1 < H2, vx0 = cx0 < W2, vx1 = cx0 + 1 < W2;
    float vals[8];
#pragma unroll
    for (int co = 0; co < 4; co++) {
        float s = 0.f, q = 0.f;
        if (vy0 && vx0) { float a = acc[co][0][0]; s += a; q = fmaf(a, a, q); }
        if (vy0 && vx1) { float a = acc[co][0][1]; s += a; q = fmaf(a, a, q); }
        if (vy1 && vx0) { float a = acc[co][1][0]; s += a; q = fmaf(a, a, q); }
        if (vy1 && vx1) { float a = acc[co][1][1]; s += a; q = fmaf(a, a, q); }
        vals[co] = s;
        vals[4 + co] = q;
    }
    if (STORE) {
        int hy = (Y0 >> 1) + ty, hx = (X0 >> 1) + tx;
        if (hy < HP && hx < WP) {
#pragma unroll
            for (int co = 0; co < 4; co++) {
                float mx = fmaxf(fmaxf(acc[co][0][0], acc[co][0][1]),
                                 fmaxf(acc[co][1][0], acc[co][1][1]));
                float mn = fminf(fminf(acc[co][0][0], acc[co][0][1]),
                                 fminf(acc[co][1][0], acc[co][1][1]));
                size_t idx = (((size_t)b * 4 + co) * HP + hy) * WP + hx;
                pmax[idx] = mx;
                pmin[idx] = mn;
            }
        }
    }
    __syncthreads();
    float* red = (float*)h1t;
    rows_reduce<8>(red, vals, tid);
    int slot = ((b * 16) + blockIdx.y * 4 + blockIdx.x) & (NS - 1);
    if (tid < 8) atomicAdd(stats2 + slot * SLOT_STRIDE + tid, red[tid * 256]);
}

// ---------------- K3: BN2+relu on pooled extrema + spatial mean + f-stat atomics ----------------
__global__ void pool_bn_mean(const float* __restrict__ pmax, const float* __restrict__ pmin,
                             const float* __restrict__ g2, const float* __restrict__ be2,
                             const float* __restrict__ stats2,
                             float* __restrict__ featbuf, float* __restrict__ gstats, float N2) {
    __shared__ float red[256];
    int co = blockIdx.x & 3;
    int b = blockIdx.x >> 2;
    int tid = threadIdx.x;
    float su = slot_sum(stats2, co), sq = slot_sum(stats2, 4 + co);
    float mu = su / N2;
    float var = sq / N2 - mu * mu;
    float sc = g2[co] * rsqrtf(var + 1e-5f);
    float sh = be2[co] - mu * sc;
    const float* P = (sc >= 0.f ? pmax : pmin) + ((size_t)b * 4 + co) * (HP * WP);
    float s = 0.f;
    for (int i = tid; i < HP * WP; i += 256) s += fmaxf(fmaf(P[i], sc, sh), 0.f);
    red[tid] = s;
    __syncthreads();
    for (int st = 128; st > 0; st >>= 1) {
        if (tid < st) red[tid] += red[tid + st];
        __syncthreads();
    }
    if (tid == 0) {
        featbuf[(size_t)b * 4 + co] = red[0];
        float f = red[0] * (1.f / (HP * WP));
        atomicAdd(gstats + 0, f);
        atomicAdd(gstats + 1, f * f);
    }
}

// ---------------- K3c (fallback): conv2 recompute + BN2 + pool + spatial sum ----------------
__global__ void conv2_final_fused(const float* __restrict__ x, const float* __restrict__ w1,
                                  const float* __restrict__ b1, const float* __restrict__ g1,
                                  const float* __restrict__ be1,
                                  const float* __restrict__ stats1,
                                  const float* __restrict__ w2, const float* __restrict__ b2,
                                  const float* __restrict__ g2, const float* __restrict__ be2,
                                  const float* __restrict__ stats2,
                                  float* __restrict__ featbuf, float N1, float N2) {
    __shared__ __align__(16) float h1t[8][34][34];
    __shared__ float sc1[8], sh1[8];
    __shared__ float sc2[4], sh2[4];
    int b = blockIdx.z;
    int py0 = blockIdx.y * 16, px0 = blockIdx.x * 16;
    int ty = threadIdx.y, tx = threadIdx.x;
    int tid = ty * 16 + tx;
    if (tid < 8) {
        float su = slot_sum(stats1, tid), sq = slot_sum(stats1, 8 + tid);
        float mu = su / N1;
        float var = sq / N1 - mu * mu;
        float sc = g1[tid] * rsqrtf(var + 1e-5f);
        sc1[tid] = sc;
        sh1[tid] = be1[tid] - mu * sc;
    }
    if (tid >= 16 && tid < 20) {
        int j = tid - 16;
        float su = slot_sum(stats2, j), sq = slot_sum(stats2, 4 + j);
        float mu = su / N2;
        float var = sq / N2 - mu * mu;
        float sc = g2[j] * rsqrtf(var + 1e-5f);
        sc2[j] = sc;
        sh2[j] = be2[j] - mu * sc;
    }
    __syncthreads();
    const float* xb = x + (size_t)b * H1 * W1;
    build_h1_tile<34, 34>(xb, h1t, w1, b1, sc1, sh1, 2 * py0 - 1, 2 * px0 - 1, tid);
    __syncthreads();
    bool valid = (py0 + ty < HP) && (px0 + tx < WP);
    float acc[4][2][2];
#pragma unroll
    for (int co = 0; co < 4; co++)
#pragma unroll
        for (int dy = 0; dy < 2; dy++)
#pragma unroll
            for (int dx = 0; dx < 2; dx++) acc[co][dy][dx] = b2[co];
#pragma unroll
    for (int ci = 0; ci < 8; ci++) {
        float win[4][4];
#pragma unroll
        for (int r = 0; r < 4; r++) {
            const float2* rp = (const float2*)&h1t[ci][2 * ty + r][2 * tx];
            float2 u = rp[0], v = rp[1];
            win[r][0] = u.x; win[r][1] = u.y; win[r][2] = v.x; win[r][3] = v.y;
        }
#pragma unroll
        for (int co = 0; co < 4; co++)
#pragma unroll
            for (int ky = 0; ky < 3; ky++)
#pragma unroll
                for (int kx = 0; kx < 3; kx++) {
                    float wv = w2[co * 72 + ci * 9 + ky * 3 + kx];
#pragma unroll
                    for (int dy = 0; dy < 2; dy++)
#pragma unroll
                        for (int dx = 0; dx < 2; dx++)
                            acc[co][dy][dx] = fmaf(wv, win[dy + ky][dx + kx], acc[co][dy][dx]);
                }
    }
    float vals[4];
#pragma unroll
    for (int co = 0; co < 4; co++) {
        float mx = -INFINITY;
#pragma unroll
        for (int dy = 0; dy < 2; dy++)
#pragma unroll
            for (int dx = 0; dx < 2; dx++)
                mx = fmaxf(mx, fmaxf(fmaf(acc[co][dy][dx], sc2[co], sh2[co]), 0.f));
        vals[co] = valid ? mx : 0.f;
    }
    __syncthreads();
    float* red = (float*)h1t;
    rows_reduce<4>(red, vals, tid);
    if (tid < 4) atomicAdd(featbuf + (size_t)b * 4 + tid, red[tid * 256]);
}

// ---------------- K4a: per-batch circuit (B blocks x 64; parallel I-fetch) ----------------
__global__ void circuit(const float* __restrict__ featbuf, const float* __restrict__ gstats,
                        const float* __restrict__ theta, const float* __restrict__ rho,
                        float* __restrict__ ebuf, float* __restrict__ gst_out, int B) {
    int b = blockIdx.x;
    float f[4];
#pragma unroll
    for (int j = 0; j < 4; j++) f[j] = featbuf[b * 4 + j] * (1.f / (HP * WP));
    float n = 4.f * (float)B;
    float mean = gstats[0] / n;
    float var1 = (gstats[1] - n * mean * mean) / (n - 1.f);
    float stdv = sqrtf(fmaxf(var1, 0.f)) + 1e-6f;
    const float PI = 3.14159265358979323846f;
    float cs[4], sn[4];
#pragma unroll
    for (int j = 0; j < 4; j++) {
        float sc = (f[j] - mean) / stdv * PI;
        cs[j] = cosf(0.5f * sc);
        sn[j] = sinf(0.5f * sc);
    }
    C2 st[16];
    {
        float amp[16];
        amp[1] = sn[3]; amp[0] = cs[3];
#pragma unroll
        for (int k = 0; k < 2; k++) { amp[k + 2] = amp[k] * sn[2]; amp[k] *= cs[2]; }
#pragma unroll
        for (int k = 0; k < 4; k++) { amp[k + 4] = amp[k] * sn[1]; amp[k] *= cs[1]; }
#pragma unroll
        for (int k = 0; k < 8; k++) { amp[k + 8] = amp[k] * sn[0]; amp[k] *= cs[0]; }
#pragma unroll
        for (int i = 0; i < 16; i++) st[i] = C2{amp[i], 0.f};
    }
#pragma clang loop unroll(disable)
    for (int l = 0; l < 2; l++) {
        const float* p = (l == 0) ? theta : rho;
#pragma clang loop unroll(disable)
        for (int i = 0; i < 4; i++) {
            M2 U = combined_u(p + i * 3);
            switch (i) {
            case 0: ap1s<8>(st, U.m[0][0], U.m[0][1], U.m[1][0], U.m[1][1]); break;
            case 1: ap1s<4>(st, U.m[0][0], U.m[0][1], U.m[1][0], U.m[1][1]); break;
            case 2: ap1s<2>(st, U.m[0][0], U.m[0][1], U.m[1][0], U.m[1][1]); break;
            default: ap1s<1>(st, U.m[0][0], U.m[0][1], U.m[1][0], U.m[1][1]); break;
            }
        }
        if (l == 0) { cnot_s<8, 4>(st); cnot_s<4, 2>(st); cnot_s<2, 1>(st); }
        else        { cnot_s<4, 8>(st); cnot_s<2, 4>(st); cnot_s<1, 2>(st); }
    }
    if (threadIdx.x == 0) {
#pragma unroll
        for (int qb = 0; qb < 4; qb++) {
            int m = 8 >> qb;
            float p0 = 0.f, p1 = 0.f;
#pragma unroll
            for (int i = 0; i < 16; i++) {
                float pr = st[i].re * st[i].re + st[i].im * st[i].im;
                if (i & m) p1 += pr; else p0 += pr;
            }
            float e = p0 - p1;
            ebuf[(size_t)b * 4 + qb] = e;
            atomicAdd(gst_out + 8 + qb, e);
            atomicAdd(gst_out + 12 + qb, e * e);
        }
    }
}

// ---------------- K4b: final batch-norm ----------------
__global__ void bn_out(const float* __restrict__ ebuf, const float* __restrict__ gstats,
                       const float* __restrict__ ng, const float* __restrict__ nb,
                       float* __restrict__ out, int B) {
    int b = threadIdx.x;
#pragma clang loop unroll(disable)
    for (int j = 0; j < 4; j++) {
        float mu = gstats[8 + j] / (float)B;
        float v = gstats[12 + j] / (float)B - mu * mu;
        float e = ebuf[(size_t)b * 4 + j];
        out[b * 4 + j] = fmaf(e - mu, rsqrtf(fmaxf(v, 0.f) + 1e-5f) * ng[j], nb[j]);
    }
}

// ---------------- fallback monolithic finalize (smallest-ws tier) ----------------
__device__ __forceinline__ float bsum(float v, float* lds) {
#pragma unroll
    for (int off = 32; off; off >>= 1) v += __shfl_xor(v, off, 64);
    __syncthreads();
    if ((threadIdx.x & 63) == 0) lds[threadIdx.x >> 6] = v;
    __syncthreads();
    float r = 0.f;
    int nw = (int)(blockDim.x + 63) >> 6;
#pragma clang loop unroll(disable)
    for (int i = 0; i < nw; i++) r += lds[i];
    return r;
}

__global__ void finalize(const float* __restrict__ featbuf, const float* __restrict__ theta,
                         const float* __restrict__ rho, const float* __restrict__ ng,
                         const float* __restrict__ nb, float* __restrict__ out, int B) {
    __shared__ float lds[16];
    int b = threadIdx.x;
    float f[4];
#pragma unroll
    for (int j = 0; j < 4; j++) f[j] = featbuf[b * 4 + j] * (1.f / (HP * WP));
    float n = 4.f * (float)B;
    float mean = bsum(f[0] + f[1] + f[2] + f[3], lds) / n;
    float d2 = 0.f;
#pragma unroll
    for (int j = 0; j < 4; j++) { float d = f[j] - mean; d2 += d * d; }
    float var1 = bsum(d2, lds) / (n - 1.f);
    float stdv = sqrtf(fmaxf(var1, 0.f)) + 1e-6f;
    const float PI = 3.14159265358979323846f;
    float cs[4], sn[4];
#pragma unroll
    for (int j = 0; j < 4; j++) {
        float sc = (f[j] - mean) / stdv * PI;
        cs[j] = cosf(0.5f * sc);
        sn[j] = sinf(0.5f * sc);
    }
    C2 st[16];
    {
        float amp[16];
        amp[1] = sn[3]; amp[0] = cs[3];
#pragma unroll
        for (int k = 0; k < 2; k++) { amp[k + 2] = amp[k] * sn[2]; amp[k] *= cs[2]; }
#pragma unroll
        for (int k = 0; k < 4; k++) { amp[k + 4] = amp[k] * sn[1]; amp[k] *= cs[1]; }
#pragma unroll
        for (int k = 0; k < 8; k++) { amp[k + 8] = amp[k] * sn[0]; amp[k] *= cs[0]; }
#pragma unroll
        for (int i = 0; i < 16; i++) st[i] = C2{amp[i], 0.f};
    }
#pragma clang loop unroll(disable)
    for (int l = 0; l < 2; l++) {
        const float* p = (l == 0) ? theta : rho;
#pragma clang loop unroll(disable)
        for (int i = 0; i < 4; i++) {
            M2 U = combined_u(p + i * 3);
            switch (i) {
            case 0: ap1s<8>(st, U.m[0][0], U.m[0][1], U.m[1][0], U.m[1][1]); break;
            case 1: ap1s<4>(st, U.m[0][0], U.m[0][1], U.m[1][0], U.m[1][1]); break;
            case 2: ap1s<2>(st, U.m[0][0], U.m[0][1], U.m[1][0], U.m[1][1]); break;
            default: ap1s<1>(st, U.m[0][0], U.m[0][1], U.m[1][0], U.m[1][1]); break;
            }
        }
        if (l == 0) { cnot_s<8, 4>(st); cnot_s<4, 2>(st); cnot_s<2, 1>(st); }
        else        { cnot_s<4, 8>(st); cnot_s<2, 4>(st); cnot_s<1, 2>(st); }
    }
    float e[4];
#pragma unroll
    for (int qb = 0; qb < 4; qb++) {
        int m = 8 >> qb;
        float p0 = 0.f, p1 = 0.f;
#pragma unroll
        for (int i = 0; i < 16; i++) {
            float pr = st[i].re * st[i].re + st[i].im * st[i].im;
            if (i & m) p1 += pr; else p0 += pr;
        }
        e[qb] = p0 - p1;
    }
#pragma clang loop unroll(disable)
    for (int j = 0; j < 4; j++) {
        float mu = bsum(e[j], lds) / (float)B;
        float dv = e[j] - mu;
        float v = bsum(dv * dv, lds) / (float)B;
        out[b * 4 + j] = fmaf(dv, rsqrtf(v + 1e-5f) * ng[j], nb[j]);
    }
}

extern "C" void kernel_launch(void* const* d_in, const int* in_sizes, int n_in,
                              void* d_out, int out_size, void* d_ws, size_t ws_size,
                              hipStream_t stream) {
    const float* x     = (const float*)d_in[0];
    const float* w1    = (const float*)d_in[1];
    const float* b1    = (const float*)d_in[2];
    const float* g1    = (const float*)d_in[3];
    const float* be1   = (const float*)d_in[4];
    const float* w2    = (const float*)d_in[5];
    const float* b2    = (const float*)d_in[6];
    const float* g2    = (const float*)d_in[7];
    const float* be2   = (const float*)d_in[8];
    const float* theta = (const float*)d_in[9];
    const float* rho   = (const float*)d_in[10];
    const float* ng    = (const float*)d_in[11];
    const float* nb    = (const float*)d_in[12];
    float* out = (float*)d_out;

    int B = in_sizes[0] / (H1 * W1);

    float* ws = (float*)d_ws;
    float* stats1 = ws;                               // NS*64
    float* stats2 = ws + NS * SLOT_STRIDE;            // NS*64
    float* gstats = ws + 2 * NS * SLOT_STRIDE;        // 64
    float* featbuf = gstats + 64;                     // B*4
    float* ebuf = featbuf + (size_t)B * 4;            // B*4
    float* bufs = ebuf + (size_t)B * 4;

    size_t common = (size_t)(2 * NS * SLOT_STRIDE + 64) + (size_t)B * 8;
    size_t p2n = (size_t)B * 4 * HP * WP;             // pooled conv2 ext
    size_t needB = (common + 2 * p2n) * sizeof(float);
    bool store = ws_size >= needB;                    // constant per process -> graph-safe

    float N1 = (float)B * H1 * W1;
    float N2 = (float)B * H2 * W2;
    int nz = (int)common;

    zero_ws<<<(nz + 255) / 256, 256, 0, stream>>>(ws, nz);
    conv1_stats<<<dim3(14, B), 256, 0, stream>>>(x, w1, b1, stats1);
    if (store) {
        float* pmax = bufs;
        float* pmin = bufs + p2n;
        conv2_stats_fused<true><<<dim3(4, 4, B), dim3(16, 16), 0, stream>>>(
            x, w1, b1, g1, be1, stats1, w2, b2, stats2, pmax, pmin, N1);
        pool_bn_mean<<<B * 4, 256, 0, stream>>>(pmax, pmin, g2, be2, stats2, featbuf, gstats, N2);
        circuit<<<B, 64, 0, stream>>>(featbuf, gstats, theta, rho, ebuf, gstats, B);
        bn_out<<<1, B, 0, stream>>>(ebuf, gstats, ng, nb, out, B);
    } else {
        conv2_stats_fused<false><<<dim3(4, 4, B), dim3(16, 16), 0, stream>>>(
            x, w1, b1, g1, be1, stats1, w2, b2, stats2, nullptr, nullptr, N1);
        conv2_final_fused<<<dim3(4, 4, B), dim3(16, 16), 0, stream>>>(
            x, w1, b1, g1, be1, stats1, w2, b2, g2, be2, stats2, featbuf, N1, N2);
        finalize<<<1, B, 0, stream>>>(featbuf, theta, rho, ng, nb, out, B);
    }
}

// Round 13
// 189.897 us; speedup vs baseline: 1.2106x; 1.1148x over previous
//
#include <hip/hip_runtime.h>
#include <math.h>

#define H1 224
#define W1 224
#define H2 112
#define W2 112
#define HP 56
#define WP 56

#define NS 32
#define SLOT_STRIDE 64

// ---------------- complex helpers (quantum circuit) ----------------
struct C2 { float re, im; };
__device__ __forceinline__ C2 cmul(C2 a, C2 b) {
    return C2{fmaf(a.re, b.re, -a.im * b.im), fmaf(a.re, b.im, a.im * b.re)};
}
__device__ __forceinline__ C2 cadd(C2 a, C2 b) { return C2{a.re + b.re, a.im + b.im}; }

template <int S>
__device__ __forceinline__ void ap1s(C2* st, C2 u00, C2 u01, C2 u10, C2 u11) {
#pragma unroll
    for (int i = 0; i < 16; i++) {
        if (i & S) continue;
        C2 a0 = st[i], a1 = st[i + S];
        st[i]     = cadd(cmul(u00, a0), cmul(u01, a1));
        st[i + S] = cadd(cmul(u10, a0), cmul(u11, a1));
    }
}
template <int SC, int STT>
__device__ __forceinline__ void cnot_s(C2* st) {
#pragma unroll
    for (int i = 0; i < 16; i++)
        if ((i & SC) && !(i & STT)) { C2 t = st[i]; st[i] = st[i + STT]; st[i + STT] = t; }
}
struct M2 { C2 m[2][2]; };
__device__ __forceinline__ M2 mmul(const M2& A, const M2& B) {
    M2 R;
#pragma unroll
    for (int i = 0; i < 2; i++)
#pragma unroll
        for (int j = 0; j < 2; j++)
            R.m[i][j] = cadd(cmul(A.m[i][0], B.m[0][j]), cmul(A.m[i][1], B.m[1][j]));
    return R;
}
// combined U = Rx(p2) * Rz(p1) * Ry(p0)
__device__ __forceinline__ M2 combined_u(const float* __restrict__ p) {
    float c0 = cosf(0.5f * p[0]), s0 = sinf(0.5f * p[0]);
    float c1 = cosf(0.5f * p[1]), s1 = sinf(0.5f * p[1]);
    float c2 = cosf(0.5f * p[2]), s2 = sinf(0.5f * p[2]);
    M2 Ry = {{{{c0, 0.f}, {-s0, 0.f}}, {{s0, 0.f}, {c0, 0.f}}}};
    M2 Rz = {{{{c1, -s1}, {0.f, 0.f}}, {{0.f, 0.f}, {c1, s1}}}};
    M2 Rx = {{{{c2, 0.f}, {0.f, -s2}}, {{0.f, -s2}, {c2, 0.f}}}};
    return mmul(Rx, mmul(Rz, Ry));
}

// ---------------- multi-row LDS tree reduction (256 threads, Q rows) ----------------
template <int Q>
__device__ __forceinline__ void rows_reduce(float* red, const float* vals, int tid) {
#pragma unroll
    for (int q = 0; q < Q; q++) red[q * 256 + tid] = vals[q];
    __syncthreads();
#pragma unroll
    for (int s = 128; s > 0; s >>= 1) {
        for (int idx = tid; idx < Q * s; idx += 256) {
            int row = idx / s, i = idx - row * s;
            red[row * 256 + i] += red[row * 256 + i + s];
        }
        __syncthreads();
    }
}

__global__ void zero_ws(float* ws, int n) {
    int i = blockIdx.x * blockDim.x + threadIdx.x;
    if (i < n) ws[i] = 0.f;
}

__device__ __forceinline__ float slot_sum(const float* stats, int c) {
    float s = 0.f;
#pragma unroll
    for (int sl = 0; sl < NS; sl++) s += stats[sl * SLOT_STRIDE + c];
    return s;
}

// ---------------- K1a (tier A): conv1 stats + pooled raw extreme, channel-last ----------------
// grid (14, B) x 256; thread = one column, 16-row strip (8 pool rows).
// p1ext layout: [b][prow][pcol][c] (c fastest, 8 floats = 32 B per cell) -> coalesced float4 x2.
__global__ void conv1_pool_stats(const float* __restrict__ x, const float* __restrict__ w,
                                 const float* __restrict__ bias, const float* __restrict__ g1,
                                 float* __restrict__ stats, float* __restrict__ p1ext) {
    __shared__ float red[16 * 256];
    int strip = blockIdx.x;
    int b = blockIdx.y;
    int tid = threadIdx.x;
    const float* xb = x + (size_t)b * H1 * W1;
    float sums[8], sqs[8], pm[8], ext8[8];
    bool gp[8];
#pragma unroll
    for (int c = 0; c < 8; c++) { sums[c] = 0.f; sqs[c] = 0.f; gp[c] = g1[c] >= 0.f; }
    int col = tid;
    if (col < W1) {
        bool cl = col > 0, cr = col < W1 - 1;
        int row0 = strip * 16;
        float a0, a1, a2, b0, b1, b2, c0, c1, c2;
        {
            int r = row0 - 1;
            if (r >= 0) {
                a0 = cl ? xb[r * W1 + col - 1] : 0.f;
                a1 = xb[r * W1 + col];
                a2 = cr ? xb[r * W1 + col + 1] : 0.f;
            } else { a0 = a1 = a2 = 0.f; }
            r = row0;
            b0 = cl ? xb[r * W1 + col - 1] : 0.f;
            b1 = xb[r * W1 + col];
            b2 = cr ? xb[r * W1 + col + 1] : 0.f;
        }
        for (int rr = 0; rr < 16; rr++) {
            int rn = row0 + rr + 1;
            if (rn < H1) {
                c0 = cl ? xb[rn * W1 + col - 1] : 0.f;
                c1 = xb[rn * W1 + col];
                c2 = cr ? xb[rn * W1 + col + 1] : 0.f;
            } else { c0 = c1 = c2 = 0.f; }
#pragma unroll
            for (int c = 0; c < 8; c++) {
                float acc = bias[c];
                acc = fmaf(w[c * 9 + 0], a0, acc);
                acc = fmaf(w[c * 9 + 1], a1, acc);
                acc = fmaf(w[c * 9 + 2], a2, acc);
                acc = fmaf(w[c * 9 + 3], b0, acc);
                acc = fmaf(w[c * 9 + 4], b1, acc);
                acc = fmaf(w[c * 9 + 5], b2, acc);
                acc = fmaf(w[c * 9 + 6], c0, acc);
                acc = fmaf(w[c * 9 + 7], c1, acc);
                acc = fmaf(w[c * 9 + 8], c2, acc);
                sums[c] += acc;
                sqs[c] = fmaf(acc, acc, sqs[c]);
                if ((rr & 1) == 0) {
                    pm[c] = acc;
                } else {
                    float m = gp[c] ? fmaxf(pm[c], acc) : fminf(pm[c], acc);
                    float mo = __shfl_xor(m, 1, 64);
                    ext8[c] = gp[c] ? fmaxf(m, mo) : fminf(m, mo);
                }
            }
            if ((rr & 1) == 1 && (col & 1) == 0) {
                int prow = strip * 8 + (rr >> 1);
                int pcol = col >> 1;
                float* dst = p1ext + ((((size_t)b * H2 + prow) * W2 + pcol) << 3);
                ((float4*)dst)[0] = make_float4(ext8[0], ext8[1], ext8[2], ext8[3]);
                ((float4*)dst)[1] = make_float4(ext8[4], ext8[5], ext8[6], ext8[7]);
            }
            a0 = b0; a1 = b1; a2 = b2;
            b0 = c0; b1 = c1; b2 = c2;
        }
    }
    float vals[16];
#pragma unroll
    for (int c = 0; c < 8; c++) { vals[c] = sums[c]; vals[8 + c] = sqs[c]; }
    rows_reduce<16>(red, vals, tid);
    int slot = (b * 14 + strip) & (NS - 1);
    if (tid < 16) atomicAdd(stats + slot * SLOT_STRIDE + tid, red[tid * 256]);
}

// ---------------- K1b (tier B/C): conv1 stats only ----------------
__global__ void conv1_stats(const float* __restrict__ x, const float* __restrict__ w,
                            const float* __restrict__ bias, float* __restrict__ stats) {
    __shared__ float red[16 * 256];
    int strip = blockIdx.x;
    int b = blockIdx.y;
    int tid = threadIdx.x;
    const float* xb = x + (size_t)b * H1 * W1;
    float sums[8], sqs[8];
#pragma unroll
    for (int c = 0; c < 8; c++) { sums[c] = 0.f; sqs[c] = 0.f; }
    int col = tid;
    if (col < W1) {
        bool cl = col > 0, cr = col < W1 - 1;
        int row0 = strip * 16;
        float a0, a1, a2, b0, b1, b2, c0, c1, c2;
        {
            int r = row0 - 1;
            if (r >= 0) {
                a0 = cl ? xb[r * W1 + col - 1] : 0.f;
                a1 = xb[r * W1 + col];
                a2 = cr ? xb[r * W1 + col + 1] : 0.f;
            } else { a0 = a1 = a2 = 0.f; }
            r = row0;
            b0 = cl ? xb[r * W1 + col - 1] : 0.f;
            b1 = xb[r * W1 + col];
            b2 = cr ? xb[r * W1 + col + 1] : 0.f;
        }
        for (int rr = 0; rr < 16; rr++) {
            int rn = row0 + rr + 1;
            if (rn < H1) {
                c0 = cl ? xb[rn * W1 + col - 1] : 0.f;
                c1 = xb[rn * W1 + col];
                c2 = cr ? xb[rn * W1 + col + 1] : 0.f;
            } else { c0 = c1 = c2 = 0.f; }
#pragma unroll
            for (int c = 0; c < 8; c++) {
                float acc = bias[c];
                acc = fmaf(w[c * 9 + 0], a0, acc);
                acc = fmaf(w[c * 9 + 1], a1, acc);
                acc = fmaf(w[c * 9 + 2], a2, acc);
                acc = fmaf(w[c * 9 + 3], b0, acc);
                acc = fmaf(w[c * 9 + 4], b1, acc);
                acc = fmaf(w[c * 9 + 5], b2, acc);
                acc = fmaf(w[c * 9 + 6], c0, acc);
                acc = fmaf(w[c * 9 + 7], c1, acc);
                acc = fmaf(w[c * 9 + 8], c2, acc);
                sums[c] += acc;
                sqs[c] = fmaf(acc, acc, sqs[c]);
            }
            a0 = b0; a1 = b1; a2 = b2;
            b0 = c0; b1 = c1; b2 = c2;
        }
    }
    float vals[16];
#pragma unroll
    for (int c = 0; c < 8; c++) { vals[c] = sums[c]; vals[8 + c] = sqs[c]; }
    rows_reduce<16>(red, vals, tid);
    int slot = (b * 14 + strip) & (NS - 1);
    if (tid < 16) atomicAdd(stats + slot * SLOT_STRIDE + tid, red[tid * 256]);
}

// build h1 tile by conv1 recompute (tier B/C)
template <int PH, int PW>
__device__ __forceinline__ void build_h1_tile(const float* __restrict__ xb,
                                              float (*h1t)[PH][PW],
                                              const float* __restrict__ w1,
                                              const float* __restrict__ b1,
                                              const float* sc1, const float* sh1,
                                              int oy0, int ox0, int tid) {
    for (int i = tid; i < PH * PW; i += 256) {
        int p = i / PW, q = i % PW;
        int hy = oy0 + p, hx = ox0 + q;
        bool ok = (hy >= 0 && hy < H2 && hx >= 0 && hx < W2);
        float xp[5][5];
        if (hy >= 1 && hy <= H2 - 2 && hx >= 1 && hx <= W2 - 2) {
            const float* bp = xb + (2 * hy - 1) * W1 + (2 * hx - 1);
#pragma unroll
            for (int r = 0; r < 5; r++)
#pragma unroll
                for (int c = 0; c < 5; c++) xp[r][c] = bp[r * W1 + c];
        } else if (ok) {
#pragma unroll
            for (int r = 0; r < 5; r++)
#pragma unroll
                for (int c = 0; c < 5; c++) {
                    int gy = 2 * hy - 1 + r, gx = 2 * hx - 1 + c;
                    xp[r][c] = (gy >= 0 && gy < H1 && gx >= 0 && gx < W1) ? xb[gy * W1 + gx] : 0.f;
                }
        }
#pragma unroll
        for (int c = 0; c < 8; c++) {
            float mx = 0.f;
            if (ok) {
                mx = -INFINITY;
#pragma unroll
                for (int dy = 0; dy < 2; dy++)
#pragma unroll
                    for (int dx = 0; dx < 2; dx++) {
                        float acc = b1[c];
#pragma unroll
                        for (int ky = 0; ky < 3; ky++)
#pragma unroll
                            for (int kx = 0; kx < 3; kx++)
                                acc = fmaf(w1[c * 9 + ky * 3 + kx], xp[dy + ky][dx + kx], acc);
                        mx = fmaxf(mx, fmaxf(fmaf(acc, sc1[c], sh1[c]), 0.f));
                    }
            }
            h1t[c][p][q] = mx;
        }
    }
}

// ---------------- K2a (tier A): conv2 stats from p1ext (channel-last), 32x32 tile ----------------
__global__ __launch_bounds__(256, 4) void conv2_stats_slim(
        const float* __restrict__ p1ext, const float* __restrict__ g1,
        const float* __restrict__ be1, const float* __restrict__ stats1,
        const float* __restrict__ w2, const float* __restrict__ b2,
        const float* __restrict__ g2,
        float* __restrict__ stats2, float* __restrict__ p2ext, float N1) {
    __shared__ __align__(16) float h1t[8][34][34];
    __shared__ float sc1[8], sh1[8];
    int b = blockIdx.z;
    int Y0 = blockIdx.y * 32, X0 = blockIdx.x * 32;
    int ty = threadIdx.y, tx = threadIdx.x;
    int tid = ty * 16 + tx;
    if (tid < 8) {
        float su = slot_sum(stats1, tid), sq = slot_sum(stats1, 8 + tid);
        float mu = su / N1;
        float var = sq / N1 - mu * mu;
        float sc = g1[tid] * rsqrtf(var + 1e-5f);
        sc1[tid] = sc;
        sh1[tid] = be1[tid] - mu * sc;
    }
    __syncthreads();
    // stage h1 tile: 1 cell = 8 consecutive floats in p1ext; BN+relu on load
    const float* pb = p1ext + (((size_t)b * H2) * W2 << 3);
    for (int i = tid; i < 34 * 34; i += 256) {
        int p = i / 34, q = i % 34;
        int hy = Y0 - 1 + p, hx = X0 - 1 + q;
        if (hy >= 0 && hy < H2 && hx >= 0 && hx < W2) {
            const float* cp = pb + (((size_t)hy * W2 + hx) << 3);
            float4 u = ((const float4*)cp)[0];
            float4 v = ((const float4*)cp)[1];
            h1t[0][p][q] = fmaxf(fmaf(u.x, sc1[0], sh1[0]), 0.f);
            h1t[1][p][q] = fmaxf(fmaf(u.y, sc1[1], sh1[1]), 0.f);
            h1t[2][p][q] = fmaxf(fmaf(u.z, sc1[2], sh1[2]), 0.f);
            h1t[3][p][q] = fmaxf(fmaf(u.w, sc1[3], sh1[3]), 0.f);
            h1t[4][p][q] = fmaxf(fmaf(v.x, sc1[4], sh1[4]), 0.f);
            h1t[5][p][q] = fmaxf(fmaf(v.y, sc1[5], sh1[5]), 0.f);
            h1t[6][p][q] = fmaxf(fmaf(v.z, sc1[6], sh1[6]), 0.f);
            h1t[7][p][q] = fmaxf(fmaf(v.w, sc1[7], sh1[7]), 0.f);
        } else {
#pragma unroll
            for (int c = 0; c < 8; c++) h1t[c][p][q] = 0.f;
        }
    }
    __syncthreads();
    float acc[4][2][2];
#pragma unroll
    for (int co = 0; co < 4; co++)
#pragma unroll
        for (int dy = 0; dy < 2; dy++)
#pragma unroll
            for (int dx = 0; dx < 2; dx++) acc[co][dy][dx] = b2[co];
#pragma unroll
    for (int ci = 0; ci < 8; ci++) {
        float win[4][4];
#pragma unroll
        for (int r = 0; r < 4; r++) {
            const float2* rp = (const float2*)&h1t[ci][2 * ty + r][2 * tx];
            float2 u = rp[0], v = rp[1];
            win[r][0] = u.x; win[r][1] = u.y; win[r][2] = v.x; win[r][3] = v.y;
        }
#pragma unroll
        for (int co = 0; co < 4; co++)
#pragma unroll
            for (int ky = 0; ky < 3; ky++)
#pragma unroll
                for (int kx = 0; kx < 3; kx++) {
                    float wv = w2[co * 72 + ci * 9 + ky * 3 + kx];
#pragma unroll
                    for (int dy = 0; dy < 2; dy++)
#pragma unroll
                        for (int dx = 0; dx < 2; dx++)
                            acc[co][dy][dx] = fmaf(wv, win[dy + ky][dx + kx], acc[co][dy][dx]);
                }
    }
    int cy0 = Y0 + 2 * ty, cx0 = X0 + 2 * tx;
    bool vy0 = cy0 < H2, vy1 = cy0 + 1 < H2, vx0 = cx0 < W2, vx1 = cx0 + 1 < W2;
    float vals[8];
#pragma unroll
    for (int co = 0; co < 4; co++) {
        float s = 0.f, q = 0.f;
        if (vy0 && vx0) { float a = acc[co][0][0]; s += a; q = fmaf(a, a, q); }
        if (vy0 && vx1) { float a = acc[co][0][1]; s += a; q = fmaf(a, a, q); }
        if (vy1 && vx0) { float a = acc[co][1][0]; s += a; q = fmaf(a, a, q); }
        if (vy1 && vx1) { float a = acc[co][1][1]; s += a; q = fmaf(a, a, q); }
        vals[co] = s;
        vals[4 + co] = q;
    }
    {
        int hy = (Y0 >> 1) + ty, hx = (X0 >> 1) + tx;
        if (hy < HP && hx < WP) {
#pragma unroll
            for (int co = 0; co < 4; co++) {
                float mx = fmaxf(fmaxf(acc[co][0][0], acc[co][0][1]),
                                 fmaxf(acc[co][1][0], acc[co][1][1]));
                float mn = fminf(fminf(acc[co][0][0], acc[co][0][1]),
                                 fminf(acc[co][1][0], acc[co][1][1]));
                p2ext[(((size_t)b * 4 + co) * HP + hy) * WP + hx] = (g2[co] >= 0.f) ? mx : mn;
            }
        }
    }
    __syncthreads();
    float* red = (float*)h1t;
    rows_reduce<8>(red, vals, tid);
    int slot = ((b * 16) + blockIdx.y * 4 + blockIdx.x) & (NS - 1);
    if (tid < 8) atomicAdd(stats2 + slot * SLOT_STRIDE + tid, red[tid * 256]);
}

// ---------------- K2b (tier B): conv2 stats with conv1 recompute + pmax/pmin ----------------
template <bool STORE>
__global__ __launch_bounds__(256, 4) void conv2_stats_fused(
        const float* __restrict__ x, const float* __restrict__ w1,
        const float* __restrict__ b1, const float* __restrict__ g1,
        const float* __restrict__ be1, const float* __restrict__ stats1,
        const float* __restrict__ w2, const float* __restrict__ b2,
        float* __restrict__ stats2,
        float* __restrict__ pmax, float* __restrict__ pmin, float N1) {
    __shared__ __align__(16) float h1t[8][34][34];
    __shared__ float sc1[8], sh1[8];
    int b = blockIdx.z;
    int Y0 = blockIdx.y * 32, X0 = blockIdx.x * 32;
    int ty = threadIdx.y, tx = threadIdx.x;
    int tid = ty * 16 + tx;
    if (tid < 8) {
        float su = slot_sum(stats1, tid), sq = slot_sum(stats1, 8 + tid);
        float mu = su / N1;
        float var = sq / N1 - mu * mu;
        float sc = g1[tid] * rsqrtf(var + 1e-5f);
        sc1[tid] = sc;
        sh1[tid] = be1[tid] - mu * sc;
    }
    __syncthreads();
    const float* xb = x + (size_t)b * H1 * W1;
    build_h1_tile<34, 34>(xb, h1t, w1, b1, sc1, sh1, Y0 - 1, X0 - 1, tid);
    __syncthreads();
    float acc[4][2][2];
#pragma unroll
    for (int co = 0; co < 4; co++)
#pragma unroll
        for (int dy = 0; dy < 2; dy++)
#pragma unroll
            for (int dx = 0; dx < 2; dx++) acc[co][dy][dx] = b2[co];
#pragma unroll
    for (int ci = 0; ci < 8; ci++) {
        float win[4][4];
#pragma unroll
        for (int r = 0; r < 4; r++) {
            const float2* rp = (const float2*)&h1t[ci][2 * ty + r][2 * tx];
            float2 u = rp[0], v = rp[1];
            win[r][0] = u.x; win[r][1] = u.y; win[r][2] = v.x; win[r][3] = v.y;
        }
#pragma unroll
        for (int co = 0; co < 4; co++)
#pragma unroll
            for (int ky = 0; ky < 3; ky++)
#pragma unroll
                for (int kx = 0; kx < 3; kx++) {
                    float wv = w2[co * 72 + ci * 9 + ky * 3 + kx];
#pragma unroll
                    for (int dy = 0; dy < 2; dy++)
#pragma unroll
                        for (int dx = 0; dx < 2; dx++)
                            acc[co][dy][dx] = fmaf(wv, win[dy + ky][dx + kx], acc[co][dy][dx]);
                }
    }
    int cy0 = Y0 + 2 * ty, cx0 = X0 + 2 * tx;
    bool vy0 = cy0 < H2, vy1 = cy0 + 1 < H2, vx0 = cx0 < W2, vx1 = cx0 + 1 < W2;
    float vals[8];
#pragma unroll
    for (int co = 0; co < 4; co++) {
        float s = 0.f, q = 0.f;
        if (vy0 && vx0) { float a = acc[co][0][0]; s += a; q = fmaf(a, a, q); }
        if (vy0 && vx1) { float a = acc[co][0][1]; s += a; q = fmaf(a, a, q); }
        if (vy1 && vx0) { float a = acc[co][1][0]; s += a; q = fmaf(a, a, q); }
        if (vy1 && vx1) { float a = acc[co][1][1]; s += a; q = fmaf(a, a, q); }
        vals[co] = s;
        vals[4 + co] = q;
    }
    if (STORE) {
        int hy = (Y0 >> 1) + ty, hx = (X0 >> 1) + tx;
        if (hy < HP && hx < WP) {
#pragma unroll
            for (int co = 0; co < 4; co++) {
                float mx = fmaxf(fmaxf(acc[co][0][0], acc[co][0][1]),
                                 fmaxf(acc[co][1][0], acc[co][1][1]));
                float mn = fminf(fminf(acc[co][0][0], acc[co][0][1]),
                                 fminf(acc[co][1][0], acc[co][1][1]));
                size_t idx = (((size_t)b * 4 + co) * HP + hy) * WP + hx;
                pmax[idx] = mx;
                pmin[idx] = mn;
            }
        }
    }
    __syncthreads();
    float* red = (float*)h1t;
    rows_reduce<8>(red, vals, tid);
    int slot = ((b * 16) + blockIdx.y * 4 + blockIdx.x) & (NS - 1);
    if (tid < 8) atomicAdd(stats2 + slot * SLOT_STRIDE + tid, red[tid * 256]);
}

// ---------------- K3: BN2+relu on pooled extrema + spatial mean ----------------
__global__ void pool_bn_mean(const float* __restrict__ pmax, const float* __restrict__ pmin,
                             const float* __restrict__ g2, const float* __restrict__ be2,
                             const float* __restrict__ stats2,
                             float* __restrict__ featbuf, float N2) {
    __shared__ float red[256];
    int co = blockIdx.x & 3;
    int b = blockIdx.x >> 2;
    int tid = threadIdx.x;
    float su = slot_sum(stats2, co), sq = slot_sum(stats2, 4 + co);
    float mu = su / N2;
    float var = sq / N2 - mu * mu;
    float sc = g2[co] * rsqrtf(var + 1e-5f);
    float sh = be2[co] - mu * sc;
    const float* P = (sc >= 0.f ? pmax : pmin) + ((size_t)b * 4 + co) * (HP * WP);
    float s = 0.f;
    for (int i = tid; i < HP * WP; i += 256) s += fmaxf(fmaf(P[i], sc, sh), 0.f);
    red[tid] = s;
    __syncthreads();
    for (int st = 128; st > 0; st >>= 1) {
        if (tid < st) red[tid] += red[tid + st];
        __syncthreads();
    }
    if (tid == 0) featbuf[(size_t)b * 4 + co] = red[0];
}

// ---------------- K3c (tier C): conv2 recompute + BN2 + pool + spatial sum ----------------
__global__ void conv2_final_fused(const float* __restrict__ x, const float* __restrict__ w1,
                                  const float* __restrict__ b1, const float* __restrict__ g1,
                                  const float* __restrict__ be1,
                                  const float* __restrict__ stats1,
                                  const float* __restrict__ w2, const float* __restrict__ b2,
                                  const float* __restrict__ g2, const float* __restrict__ be2,
                                  const float* __restrict__ stats2,
                                  float* __restrict__ featbuf, float N1, float N2) {
    __shared__ __align__(16) float h1t[8][34][34];
    __shared__ float sc1[8], sh1[8];
    __shared__ float sc2[4], sh2[4];
    int b = blockIdx.z;
    int py0 = blockIdx.y * 16, px0 = blockIdx.x * 16;
    int ty = threadIdx.y, tx = threadIdx.x;
    int tid = ty * 16 + tx;
    if (tid < 8) {
        float su = slot_sum(stats1, tid), sq = slot_sum(stats1, 8 + tid);
        float mu = su / N1;
        float var = sq / N1 - mu * mu;
        float sc = g1[tid] * rsqrtf(var + 1e-5f);
        sc1[tid] = sc;
        sh1[tid] = be1[tid] - mu * sc;
    }
    if (tid >= 16 && tid < 20) {
        int j = tid - 16;
        float su = slot_sum(stats2, j), sq = slot_sum(stats2, 4 + j);
        float mu = su / N2;
        float var = sq / N2 - mu * mu;
        float sc = g2[j] * rsqrtf(var + 1e-5f);
        sc2[j] = sc;
        sh2[j] = be2[j] - mu * sc;
    }
    __syncthreads();
    const float* xb = x + (size_t)b * H1 * W1;
    build_h1_tile<34, 34>(xb, h1t, w1, b1, sc1, sh1, 2 * py0 - 1, 2 * px0 - 1, tid);
    __syncthreads();
    bool valid = (py0 + ty < HP) && (px0 + tx < WP);
    float acc[4][2][2];
#pragma unroll
    for (int co = 0; co < 4; co++)
#pragma unroll
        for (int dy = 0; dy < 2; dy++)
#pragma unroll
            for (int dx = 0; dx < 2; dx++) acc[co][dy][dx] = b2[co];
#pragma unroll
    for (int ci = 0; ci < 8; ci++) {
        float win[4][4];
#pragma unroll
        for (int r = 0; r < 4; r++) {
            const float2* rp = (const float2*)&h1t[ci][2 * ty + r][2 * tx];
            float2 u = rp[0], v = rp[1];
            win[r][0] = u.x; win[r][1] = u.y; win[r][2] = v.x; win[r][3] = v.y;
        }
#pragma unroll
        for (int co = 0; co < 4; co++)
#pragma unroll
            for (int ky = 0; ky < 3; ky++)
#pragma unroll
                for (int kx = 0; kx < 3; kx++) {
                    float wv = w2[co * 72 + ci * 9 + ky * 3 + kx];
#pragma unroll
                    for (int dy = 0; dy < 2; dy++)
#pragma unroll
                        for (int dx = 0; dx < 2; dx++)
                            acc[co][dy][dx] = fmaf(wv, win[dy + ky][dx + kx], acc[co][dy][dx]);
                }
    }
    float vals[4];
#pragma unroll
    for (int co = 0; co < 4; co++) {
        float mx = -INFINITY;
#pragma unroll
        for (int dy = 0; dy < 2; dy++)
#pragma unroll
            for (int dx = 0; dx < 2; dx++)
                mx = fmaxf(mx, fmaxf(fmaf(acc[co][dy][dx], sc2[co], sh2[co]), 0.f));
        vals[co] = valid ? mx : 0.f;
    }
    __syncthreads();
    float* red = (float*)h1t;
    rows_reduce<4>(red, vals, tid);
    if (tid < 4) atomicAdd(featbuf + (size_t)b * 4 + tid, red[tid * 256]);
}

// ---------------- K4: monolithic standardize + circuit + batch BN (R10-proven) ----------------
__device__ __forceinline__ float bsum(float v, float* lds) {
#pragma unroll
    for (int off = 32; off; off >>= 1) v += __shfl_xor(v, off, 64);
    __syncthreads();
    if ((threadIdx.x & 63) == 0) lds[threadIdx.x >> 6] = v;
    __syncthreads();
    float r = 0.f;
    int nw = (int)(blockDim.x + 63) >> 6;
#pragma clang loop unroll(disable)
    for (int i = 0; i < nw; i++) r += lds[i];
    return r;
}

__global__ void finalize(const float* __restrict__ featbuf, const float* __restrict__ theta,
                         const float* __restrict__ rho, const float* __restrict__ ng,
                         const float* __restrict__ nb, float* __restrict__ out, int B) {
    __shared__ float lds[16];
    int b = threadIdx.x;
    float f[4];
#pragma unroll
    for (int j = 0; j < 4; j++) f[j] = featbuf[b * 4 + j] * (1.f / (HP * WP));
    float n = 4.f * (float)B;
    float mean = bsum(f[0] + f[1] + f[2] + f[3], lds) / n;
    float d2 = 0.f;
#pragma unroll
    for (int j = 0; j < 4; j++) { float d = f[j] - mean; d2 += d * d; }
    float var1 = bsum(d2, lds) / (n - 1.f);
    float stdv = sqrtf(fmaxf(var1, 0.f)) + 1e-6f;
    const float PI = 3.14159265358979323846f;
    float cs[4], sn[4];
#pragma unroll
    for (int j = 0; j < 4; j++) {
        float sc = (f[j] - mean) / stdv * PI;
        cs[j] = cosf(0.5f * sc);
        sn[j] = sinf(0.5f * sc);
    }
    C2 st[16];
    {
        float amp[16];
        amp[1] = sn[3]; amp[0] = cs[3];
#pragma unroll
        for (int k = 0; k < 2; k++) { amp[k + 2] = amp[k] * sn[2]; amp[k] *= cs[2]; }
#pragma unroll
        for (int k = 0; k < 4; k++) { amp[k + 4] = amp[k] * sn[1]; amp[k] *= cs[1]; }
#pragma unroll
        for (int k = 0; k < 8; k++) { amp[k + 8] = amp[k] * sn[0]; amp[k] *= cs[0]; }
#pragma unroll
        for (int i = 0; i < 16; i++) st[i] = C2{amp[i], 0.f};
    }
#pragma clang loop unroll(disable)
    for (int l = 0; l < 2; l++) {
        const float* p = (l == 0) ? theta : rho;
#pragma clang loop unroll(disable)
        for (int i = 0; i < 4; i++) {
            M2 U = combined_u(p + i * 3);
            switch (i) {
            case 0: ap1s<8>(st, U.m[0][0], U.m[0][1], U.m[1][0], U.m[1][1]); break;
            case 1: ap1s<4>(st, U.m[0][0], U.m[0][1], U.m[1][0], U.m[1][1]); break;
            case 2: ap1s<2>(st, U.m[0][0], U.m[0][1], U.m[1][0], U.m[1][1]); break;
            default: ap1s<1>(st, U.m[0][0], U.m[0][1], U.m[1][0], U.m[1][1]); break;
            }
        }
        if (l == 0) { cnot_s<8, 4>(st); cnot_s<4, 2>(st); cnot_s<2, 1>(st); }
        else        { cnot_s<4, 8>(st); cnot_s<2, 4>(st); cnot_s<1, 2>(st); }
    }
    float e[4];
#pragma unroll
    for (int qb = 0; qb < 4; qb++) {
        int m = 8 >> qb;
        float p0 = 0.f, p1 = 0.f;
#pragma unroll
        for (int i = 0; i < 16; i++) {
            float pr = st[i].re * st[i].re + st[i].im * st[i].im;
            if (i & m) p1 += pr; else p0 += pr;
        }
        e[qb] = p0 - p1;
    }
#pragma clang loop unroll(disable)
    for (int j = 0; j < 4; j++) {
        float mu = bsum(e[j], lds) / (float)B;
        float dv = e[j] - mu;
        float v = bsum(dv * dv, lds) / (float)B;
        out[b * 4 + j] = fmaf(dv, rsqrtf(v + 1e-5f) * ng[j], nb[j]);
    }
}

extern "C" void kernel_launch(void* const* d_in, const int* in_sizes, int n_in,
                              void* d_out, int out_size, void* d_ws, size_t ws_size,
                              hipStream_t stream) {
    const float* x     = (const float*)d_in[0];
    const float* w1    = (const float*)d_in[1];
    const float* b1    = (const float*)d_in[2];
    const float* g1    = (const float*)d_in[3];
    const float* be1   = (const float*)d_in[4];
    const float* w2    = (const float*)d_in[5];
    const float* b2    = (const float*)d_in[6];
    const float* g2    = (const float*)d_in[7];
    const float* be2   = (const float*)d_in[8];
    const float* theta = (const float*)d_in[9];
    const float* rho   = (const float*)d_in[10];
    const float* ng    = (const float*)d_in[11];
    const float* nb    = (const float*)d_in[12];
    float* out = (float*)d_out;

    int B = in_sizes[0] / (H1 * W1);

    float* ws = (float*)d_ws;
    float* stats1 = ws;                               // NS*64
    float* stats2 = ws + NS * SLOT_STRIDE;            // NS*64
    float* featbuf = ws + 2 * NS * SLOT_STRIDE;       // B*4
    float* bufs = featbuf + (size_t)B * 4;

    size_t common = (size_t)(2 * NS * SLOT_STRIDE) + (size_t)B * 4;
    size_t p2n = (size_t)B * 4 * HP * WP;             // pooled conv2 ext (one plane)
    size_t p1n = (size_t)B * 8 * H2 * W2;             // pooled conv1 ext, channel-last
    size_t needA = (common + p2n + p1n) * sizeof(float);
    size_t needB = (common + 2 * p2n) * sizeof(float);
    bool tierA = ws_size >= needA;                    // constant per process -> graph-safe
    bool tierB = !tierA && ws_size >= needB;

    float N1 = (float)B * H1 * W1;
    float N2 = (float)B * H2 * W2;
    int nz = (int)common;

    zero_ws<<<(nz + 255) / 256, 256, 0, stream>>>(ws, nz);
    if (tierA) {
        float* p2ext = bufs;
        float* p1ext = bufs + p2n;
        conv1_pool_stats<<<dim3(14, B), 256, 0, stream>>>(x, w1, b1, g1, stats1, p1ext);
        conv2_stats_slim<<<dim3(4, 4, B), dim3(16, 16), 0, stream>>>(
            p1ext, g1, be1, stats1, w2, b2, g2, stats2, p2ext, N1);
        pool_bn_mean<<<B * 4, 256, 0, stream>>>(p2ext, p2ext, g2, be2, stats2, featbuf, N2);
        finalize<<<1, B, 0, stream>>>(featbuf, theta, rho, ng, nb, out, B);
    } else if (tierB) {
        float* pmax = bufs;
        float* pmin = bufs + p2n;
        conv1_stats<<<dim3(14, B), 256, 0, stream>>>(x, w1, b1, stats1);
        conv2_stats_fused<true><<<dim3(4, 4, B), dim3(16, 16), 0, stream>>>(
            x, w1, b1, g1, be1, stats1, w2, b2, stats2, pmax, pmin, N1);
        pool_bn_mean<<<B * 4, 256, 0, stream>>>(pmax, pmin, g2, be2, stats2, featbuf, N2);
        finalize<<<1, B, 0, stream>>>(featbuf, theta, rho, ng, nb, out, B);
    } else {
        conv1_stats<<<dim3(14, B), 256, 0, stream>>>(x, w1, b1, stats1);
        conv2_stats_fused<false><<<dim3(4, 4, B), dim3(16, 16), 0, stream>>>(
            x, w1, b1, g1, be1, stats1, w2, b2, stats2, nullptr, nullptr, N1);
        conv2_final_fused<<<dim3(4, 4, B), dim3(16, 16), 0, stream>>>(
            x, w1, b1, g1, be1, stats1, w2, b2, g2, be2, stats2, featbuf, N1, N2);
        finalize<<<1, B, 0, stream>>>(featbuf, theta, rho, ng, nb, out, B);
    }
}

// Round 14
// 180.924 us; speedup vs baseline: 1.2706x; 1.0496x over previous
//
#include <hip/hip_runtime.h>
#include <math.h>

#define H1 224
#define W1 224
#define H2 112
#define W2 112
#define HP 56
#define WP 56

#define NS 32
#define SLOT_STRIDE 64

// ---------------- complex helpers (quantum circuit) ----------------
struct C2 { float re, im; };
__device__ __forceinline__ C2 cmul(C2 a, C2 b) {
    return C2{fmaf(a.re, b.re, -a.im * b.im), fmaf(a.re, b.im, a.im * b.re)};
}
__device__ __forceinline__ C2 cadd(C2 a, C2 b) { return C2{a.re + b.re, a.im + b.im}; }

template <int S>
__device__ __forceinline__ void ap1s(C2* st, C2 u00, C2 u01, C2 u10, C2 u11) {
#pragma unroll
    for (int i = 0; i < 16; i++) {
        if (i & S) continue;
        C2 a0 = st[i], a1 = st[i + S];
        st[i]     = cadd(cmul(u00, a0), cmul(u01, a1));
        st[i + S] = cadd(cmul(u10, a0), cmul(u11, a1));
    }
}
template <int SC, int STT>
__device__ __forceinline__ void cnot_s(C2* st) {
#pragma unroll
    for (int i = 0; i < 16; i++)
        if ((i & SC) && !(i & STT)) { C2 t = st[i]; st[i] = st[i + STT]; st[i + STT] = t; }
}
struct M2 { C2 m[2][2]; };
__device__ __forceinline__ M2 mmul(const M2& A, const M2& B) {
    M2 R;
#pragma unroll
    for (int i = 0; i < 2; i++)
#pragma unroll
        for (int j = 0; j < 2; j++)
            R.m[i][j] = cadd(cmul(A.m[i][0], B.m[0][j]), cmul(A.m[i][1], B.m[1][j]));
    return R;
}
// combined U = Rx(p2) * Rz(p1) * Ry(p0)
__device__ __forceinline__ M2 combined_u(const float* __restrict__ p) {
    float c0 = cosf(0.5f * p[0]), s0 = sinf(0.5f * p[0]);
    float c1 = cosf(0.5f * p[1]), s1 = sinf(0.5f * p[1]);
    float c2 = cosf(0.5f * p[2]), s2 = sinf(0.5f * p[2]);
    M2 Ry = {{{{c0, 0.f}, {-s0, 0.f}}, {{s0, 0.f}, {c0, 0.f}}}};
    M2 Rz = {{{{c1, -s1}, {0.f, 0.f}}, {{0.f, 0.f}, {c1, s1}}}};
    M2 Rx = {{{{c2, 0.f}, {0.f, -s2}}, {{0.f, -s2}, {c2, 0.f}}}};
    return mmul(Rx, mmul(Rz, Ry));
}

// ---------------- multi-row LDS tree reduction (256 threads, Q rows) ----------------
template <int Q>
__device__ __forceinline__ void rows_reduce(float* red, const float* vals, int tid) {
#pragma unroll
    for (int q = 0; q < Q; q++) red[q * 256 + tid] = vals[q];
    __syncthreads();
#pragma unroll
    for (int s = 128; s > 0; s >>= 1) {
        for (int idx = tid; idx < Q * s; idx += 256) {
            int row = idx / s, i = idx - row * s;
            red[row * 256 + i] += red[row * 256 + i + s];
        }
        __syncthreads();
    }
}

__global__ void zero_ws(float* ws, int n) {
    int i = blockIdx.x * blockDim.x + threadIdx.x;
    if (i < n) ws[i] = 0.f;
}

__device__ __forceinline__ float slot_sum(const float* stats, int c) {
    float s = 0.f;
#pragma unroll
    for (int sl = 0; sl < NS; sl++) s += stats[sl * SLOT_STRIDE + c];
    return s;
}

// ---------------- K1a (tier A): conv1 stats + pooled raw extreme, channel-last ----------------
// grid (28, B) x 256; thread = one column, 8-row strip (4 pool rows).
// p1ext layout: [b][prow][pcol][c] (c fastest, 8 floats = 32 B per cell) -> coalesced float4 x2.
__global__ void conv1_pool_stats(const float* __restrict__ x, const float* __restrict__ w,
                                 const float* __restrict__ bias, const float* __restrict__ g1,
                                 float* __restrict__ stats, float* __restrict__ p1ext) {
    __shared__ float red[16 * 256];
    int strip = blockIdx.x;
    int b = blockIdx.y;
    int tid = threadIdx.x;
    const float* xb = x + (size_t)b * H1 * W1;
    float sums[8], sqs[8], pm[8], ext8[8];
    bool gp[8];
#pragma unroll
    for (int c = 0; c < 8; c++) { sums[c] = 0.f; sqs[c] = 0.f; gp[c] = g1[c] >= 0.f; }
    int col = tid;
    if (col < W1) {
        bool cl = col > 0, cr = col < W1 - 1;
        int row0 = strip * 8;
        float a0, a1, a2, b0, b1, b2, c0, c1, c2;
        {
            int r = row0 - 1;
            if (r >= 0) {
                a0 = cl ? xb[r * W1 + col - 1] : 0.f;
                a1 = xb[r * W1 + col];
                a2 = cr ? xb[r * W1 + col + 1] : 0.f;
            } else { a0 = a1 = a2 = 0.f; }
            r = row0;
            b0 = cl ? xb[r * W1 + col - 1] : 0.f;
            b1 = xb[r * W1 + col];
            b2 = cr ? xb[r * W1 + col + 1] : 0.f;
        }
        for (int rr = 0; rr < 8; rr++) {
            int rn = row0 + rr + 1;
            if (rn < H1) {
                c0 = cl ? xb[rn * W1 + col - 1] : 0.f;
                c1 = xb[rn * W1 + col];
                c2 = cr ? xb[rn * W1 + col + 1] : 0.f;
            } else { c0 = c1 = c2 = 0.f; }
#pragma unroll
            for (int c = 0; c < 8; c++) {
                float acc = bias[c];
                acc = fmaf(w[c * 9 + 0], a0, acc);
                acc = fmaf(w[c * 9 + 1], a1, acc);
                acc = fmaf(w[c * 9 + 2], a2, acc);
                acc = fmaf(w[c * 9 + 3], b0, acc);
                acc = fmaf(w[c * 9 + 4], b1, acc);
                acc = fmaf(w[c * 9 + 5], b2, acc);
                acc = fmaf(w[c * 9 + 6], c0, acc);
                acc = fmaf(w[c * 9 + 7], c1, acc);
                acc = fmaf(w[c * 9 + 8], c2, acc);
                sums[c] += acc;
                sqs[c] = fmaf(acc, acc, sqs[c]);
                if ((rr & 1) == 0) {
                    pm[c] = acc;
                } else {
                    float m = gp[c] ? fmaxf(pm[c], acc) : fminf(pm[c], acc);
                    float mo = __shfl_xor(m, 1, 64);
                    ext8[c] = gp[c] ? fmaxf(m, mo) : fminf(m, mo);
                }
            }
            if ((rr & 1) == 1 && (col & 1) == 0) {
                int prow = strip * 4 + (rr >> 1);
                int pcol = col >> 1;
                float* dst = p1ext + ((((size_t)b * H2 + prow) * W2 + pcol) << 3);
                ((float4*)dst)[0] = make_float4(ext8[0], ext8[1], ext8[2], ext8[3]);
                ((float4*)dst)[1] = make_float4(ext8[4], ext8[5], ext8[6], ext8[7]);
            }
            a0 = b0; a1 = b1; a2 = b2;
            b0 = c0; b1 = c1; b2 = c2;
        }
    }
    float vals[16];
#pragma unroll
    for (int c = 0; c < 8; c++) { vals[c] = sums[c]; vals[8 + c] = sqs[c]; }
    rows_reduce<16>(red, vals, tid);
    int slot = (b * 28 + strip) & (NS - 1);
    if (tid < 16) atomicAdd(stats + slot * SLOT_STRIDE + tid, red[tid * 256]);
}

// ---------------- K1b (tier B/C): conv1 stats only, 8-row strips ----------------
__global__ void conv1_stats(const float* __restrict__ x, const float* __restrict__ w,
                            const float* __restrict__ bias, float* __restrict__ stats) {
    __shared__ float red[16 * 256];
    int strip = blockIdx.x;
    int b = blockIdx.y;
    int tid = threadIdx.x;
    const float* xb = x + (size_t)b * H1 * W1;
    float sums[8], sqs[8];
#pragma unroll
    for (int c = 0; c < 8; c++) { sums[c] = 0.f; sqs[c] = 0.f; }
    int col = tid;
    if (col < W1) {
        bool cl = col > 0, cr = col < W1 - 1;
        int row0 = strip * 8;
        float a0, a1, a2, b0, b1, b2, c0, c1, c2;
        {
            int r = row0 - 1;
            if (r >= 0) {
                a0 = cl ? xb[r * W1 + col - 1] : 0.f;
                a1 = xb[r * W1 + col];
                a2 = cr ? xb[r * W1 + col + 1] : 0.f;
            } else { a0 = a1 = a2 = 0.f; }
            r = row0;
            b0 = cl ? xb[r * W1 + col - 1] : 0.f;
            b1 = xb[r * W1 + col];
            b2 = cr ? xb[r * W1 + col + 1] : 0.f;
        }
        for (int rr = 0; rr < 8; rr++) {
            int rn = row0 + rr + 1;
            if (rn < H1) {
                c0 = cl ? xb[rn * W1 + col - 1] : 0.f;
                c1 = xb[rn * W1 + col];
                c2 = cr ? xb[rn * W1 + col + 1] : 0.f;
            } else { c0 = c1 = c2 = 0.f; }
#pragma unroll
            for (int c = 0; c < 8; c++) {
                float acc = bias[c];
                acc = fmaf(w[c * 9 + 0], a0, acc);
                acc = fmaf(w[c * 9 + 1], a1, acc);
                acc = fmaf(w[c * 9 + 2], a2, acc);
                acc = fmaf(w[c * 9 + 3], b0, acc);
                acc = fmaf(w[c * 9 + 4], b1, acc);
                acc = fmaf(w[c * 9 + 5], b2, acc);
                acc = fmaf(w[c * 9 + 6], c0, acc);
                acc = fmaf(w[c * 9 + 7], c1, acc);
                acc = fmaf(w[c * 9 + 8], c2, acc);
                sums[c] += acc;
                sqs[c] = fmaf(acc, acc, sqs[c]);
            }
            a0 = b0; a1 = b1; a2 = b2;
            b0 = c0; b1 = c1; b2 = c2;
        }
    }
    float vals[16];
#pragma unroll
    for (int c = 0; c < 8; c++) { vals[c] = sums[c]; vals[8 + c] = sqs[c]; }
    rows_reduce<16>(red, vals, tid);
    int slot = (b * 28 + strip) & (NS - 1);
    if (tid < 16) atomicAdd(stats + slot * SLOT_STRIDE + tid, red[tid * 256]);
}

// build h1 tile by conv1 recompute (tier B/C)
template <int PH, int PW>
__device__ __forceinline__ void build_h1_tile(const float* __restrict__ xb,
                                              float (*h1t)[PH][PW],
                                              const float* __restrict__ w1,
                                              const float* __restrict__ b1,
                                              const float* sc1, const float* sh1,
                                              int oy0, int ox0, int tid) {
    for (int i = tid; i < PH * PW; i += 256) {
        int p = i / PW, q = i % PW;
        int hy = oy0 + p, hx = ox0 + q;
        bool ok = (hy >= 0 && hy < H2 && hx >= 0 && hx < W2);
        float xp[5][5];
        if (hy >= 1 && hy <= H2 - 2 && hx >= 1 && hx <= W2 - 2) {
            const float* bp = xb + (2 * hy - 1) * W1 + (2 * hx - 1);
#pragma unroll
            for (int r = 0; r < 5; r++)
#pragma unroll
                for (int c = 0; c < 5; c++) xp[r][c] = bp[r * W1 + c];
        } else if (ok) {
#pragma unroll
            for (int r = 0; r < 5; r++)
#pragma unroll
                for (int c = 0; c < 5; c++) {
                    int gy = 2 * hy - 1 + r, gx = 2 * hx - 1 + c;
                    xp[r][c] = (gy >= 0 && gy < H1 && gx >= 0 && gx < W1) ? xb[gy * W1 + gx] : 0.f;
                }
        }
#pragma unroll
        for (int c = 0; c < 8; c++) {
            float mx = 0.f;
            if (ok) {
                mx = -INFINITY;
#pragma unroll
                for (int dy = 0; dy < 2; dy++)
#pragma unroll
                    for (int dx = 0; dx < 2; dx++) {
                        float acc = b1[c];
#pragma unroll
                        for (int ky = 0; ky < 3; ky++)
#pragma unroll
                            for (int kx = 0; kx < 3; kx++)
                                acc = fmaf(w1[c * 9 + ky * 3 + kx], xp[dy + ky][dx + kx], acc);
                        mx = fmaxf(mx, fmaxf(fmaf(acc, sc1[c], sh1[c]), 0.f));
                    }
            }
            h1t[c][p][q] = mx;
        }
    }
}

// ---------------- K2a (tier A): conv2 stats from p1ext (channel-last), 32x32 tile ----------------
__global__ __launch_bounds__(256, 4) void conv2_stats_slim(
        const float* __restrict__ p1ext, const float* __restrict__ g1,
        const float* __restrict__ be1, const float* __restrict__ stats1,
        const float* __restrict__ w2, const float* __restrict__ b2,
        const float* __restrict__ g2,
        float* __restrict__ stats2, float* __restrict__ p2ext, float N1) {
    __shared__ __align__(16) float h1t[8][34][34];
    __shared__ float sc1[8], sh1[8];
    int b = blockIdx.z;
    int Y0 = blockIdx.y * 32, X0 = blockIdx.x * 32;
    int ty = threadIdx.y, tx = threadIdx.x;
    int tid = ty * 16 + tx;
    if (tid < 8) {
        float su = slot_sum(stats1, tid), sq = slot_sum(stats1, 8 + tid);
        float mu = su / N1;
        float var = sq / N1 - mu * mu;
        float sc = g1[tid] * rsqrtf(var + 1e-5f);
        sc1[tid] = sc;
        sh1[tid] = be1[tid] - mu * sc;
    }
    __syncthreads();
    // stage h1 tile: 1 cell = 8 consecutive floats in p1ext; BN+relu on load
    const float* pb = p1ext + (((size_t)b * H2) * W2 << 3);
    for (int i = tid; i < 34 * 34; i += 256) {
        int p = i / 34, q = i % 34;
        int hy = Y0 - 1 + p, hx = X0 - 1 + q;
        if (hy >= 0 && hy < H2 && hx >= 0 && hx < W2) {
            const float* cp = pb + (((size_t)hy * W2 + hx) << 3);
            float4 u = ((const float4*)cp)[0];
            float4 v = ((const float4*)cp)[1];
            h1t[0][p][q] = fmaxf(fmaf(u.x, sc1[0], sh1[0]), 0.f);
            h1t[1][p][q] = fmaxf(fmaf(u.y, sc1[1], sh1[1]), 0.f);
            h1t[2][p][q] = fmaxf(fmaf(u.z, sc1[2], sh1[2]), 0.f);
            h1t[3][p][q] = fmaxf(fmaf(u.w, sc1[3], sh1[3]), 0.f);
            h1t[4][p][q] = fmaxf(fmaf(v.x, sc1[4], sh1[4]), 0.f);
            h1t[5][p][q] = fmaxf(fmaf(v.y, sc1[5], sh1[5]), 0.f);
            h1t[6][p][q] = fmaxf(fmaf(v.z, sc1[6], sh1[6]), 0.f);
            h1t[7][p][q] = fmaxf(fmaf(v.w, sc1[7], sh1[7]), 0.f);
        } else {
#pragma unroll
            for (int c = 0; c < 8; c++) h1t[c][p][q] = 0.f;
        }
    }
    __syncthreads();
    float acc[4][2][2];
#pragma unroll
    for (int co = 0; co < 4; co++)
#pragma unroll
        for (int dy = 0; dy < 2; dy++)
#pragma unroll
            for (int dx = 0; dx < 2; dx++) acc[co][dy][dx] = b2[co];
#pragma unroll
    for (int ci = 0; ci < 8; ci++) {
        float win[4][4];
#pragma unroll
        for (int r = 0; r < 4; r++) {
            const float2* rp = (const float2*)&h1t[ci][2 * ty + r][2 * tx];
            float2 u = rp[0], v = rp[1];
            win[r][0] = u.x; win[r][1] = u.y; win[r][2] = v.x; win[r][3] = v.y;
        }
#pragma unroll
        for (int co = 0; co < 4; co++)
#pragma unroll
            for (int ky = 0; ky < 3; ky++)
#pragma unroll
                for (int kx = 0; kx < 3; kx++) {
                    float wv = w2[co * 72 + ci * 9 + ky * 3 + kx];
#pragma unroll
                    for (int dy = 0; dy < 2; dy++)
#pragma unroll
                        for (int dx = 0; dx < 2; dx++)
                            acc[co][dy][dx] = fmaf(wv, win[dy + ky][dx + kx], acc[co][dy][dx]);
                }
    }
    int cy0 = Y0 + 2 * ty, cx0 = X0 + 2 * tx;
    bool vy0 = cy0 < H2, vy1 = cy0 + 1 < H2, vx0 = cx0 < W2, vx1 = cx0 + 1 < W2;
    float vals[8];
#pragma unroll
    for (int co = 0; co < 4; co++) {
        float s = 0.f, q = 0.f;
        if (vy0 && vx0) { float a = acc[co][0][0]; s += a; q = fmaf(a, a, q); }
        if (vy0 && vx1) { float a = acc[co][0][1]; s += a; q = fmaf(a, a, q); }
        if (vy1 && vx0) { float a = acc[co][1][0]; s += a; q = fmaf(a, a, q); }
        if (vy1 && vx1) { float a = acc[co][1][1]; s += a; q = fmaf(a, a, q); }
        vals[co] = s;
        vals[4 + co] = q;
    }
    {
        int hy = (Y0 >> 1) + ty, hx = (X0 >> 1) + tx;
        if (hy < HP && hx < WP) {
#pragma unroll
            for (int co = 0; co < 4; co++) {
                float mx = fmaxf(fmaxf(acc[co][0][0], acc[co][0][1]),
                                 fmaxf(acc[co][1][0], acc[co][1][1]));
                float mn = fminf(fminf(acc[co][0][0], acc[co][0][1]),
                                 fminf(acc[co][1][0], acc[co][1][1]));
                p2ext[(((size_t)b * 4 + co) * HP + hy) * WP + hx] = (g2[co] >= 0.f) ? mx : mn;
            }
        }
    }
    __syncthreads();
    float* red = (float*)h1t;
    rows_reduce<8>(red, vals, tid);
    int slot = ((b * 16) + blockIdx.y * 4 + blockIdx.x) & (NS - 1);
    if (tid < 8) atomicAdd(stats2 + slot * SLOT_STRIDE + tid, red[tid * 256]);
}

// ---------------- K2b (tier B): conv2 stats with conv1 recompute + pmax/pmin ----------------
template <bool STORE>
__global__ __launch_bounds__(256, 4) void conv2_stats_fused(
        const float* __restrict__ x, const float* __restrict__ w1,
        const float* __restrict__ b1, const float* __restrict__ g1,
        const float* __restrict__ be1, const float* __restrict__ stats1,
        const float* __restrict__ w2, const float* __restrict__ b2,
        float* __restrict__ stats2,
        float* __restrict__ pmax, float* __restrict__ pmin, float N1) {
    __shared__ __align__(16) float h1t[8][34][34];
    __shared__ float sc1[8], sh1[8];
    int b = blockIdx.z;
    int Y0 = blockIdx.y * 32, X0 = blockIdx.x * 32;
    int ty = threadIdx.y, tx = threadIdx.x;
    int tid = ty * 16 + tx;
    if (tid < 8) {
        float su = slot_sum(stats1, tid), sq = slot_sum(stats1, 8 + tid);
        float mu = su / N1;
        float var = sq / N1 - mu * mu;
        float sc = g1[tid] * rsqrtf(var + 1e-5f);
        sc1[tid] = sc;
        sh1[tid] = be1[tid] - mu * sc;
    }
    __syncthreads();
    const float* xb = x + (size_t)b * H1 * W1;
    build_h1_tile<34, 34>(xb, h1t, w1, b1, sc1, sh1, Y0 - 1, X0 - 1, tid);
    __syncthreads();
    float acc[4][2][2];
#pragma unroll
    for (int co = 0; co < 4; co++)
#pragma unroll
        for (int dy = 0; dy < 2; dy++)
#pragma unroll
            for (int dx = 0; dx < 2; dx++) acc[co][dy][dx] = b2[co];
#pragma unroll
    for (int ci = 0; ci < 8; ci++) {
        float win[4][4];
#pragma unroll
        for (int r = 0; r < 4; r++) {
            const float2* rp = (const float2*)&h1t[ci][2 * ty + r][2 * tx];
            float2 u = rp[0], v = rp[1];
            win[r][0] = u.x; win[r][1] = u.y; win[r][2] = v.x; win[r][3] = v.y;
        }
#pragma unroll
        for (int co = 0; co < 4; co++)
#pragma unroll
            for (int ky = 0; ky < 3; ky++)
#pragma unroll
                for (int kx = 0; kx < 3; kx++) {
                    float wv = w2[co * 72 + ci * 9 + ky * 3 + kx];
#pragma unroll
                    for (int dy = 0; dy < 2; dy++)
#pragma unroll
                        for (int dx = 0; dx < 2; dx++)
                            acc[co][dy][dx] = fmaf(wv, win[dy + ky][dx + kx], acc[co][dy][dx]);
                }
    }
    int cy0 = Y0 + 2 * ty, cx0 = X0 + 2 * tx;
    bool vy0 = cy0 < H2, vy1 = cy0 + 1 < H2, vx0 = cx0 < W2, vx1 = cx0 + 1 < W2;
    float vals[8];
#pragma unroll
    for (int co = 0; co < 4; co++) {
        float s = 0.f, q = 0.f;
        if (vy0 && vx0) { float a = acc[co][0][0]; s += a; q = fmaf(a, a, q); }
        if (vy0 && vx1) { float a = acc[co][0][1]; s += a; q = fmaf(a, a, q); }
        if (vy1 && vx0) { float a = acc[co][1][0]; s += a; q = fmaf(a, a, q); }
        if (vy1 && vx1) { float a = acc[co][1][1]; s += a; q = fmaf(a, a, q); }
        vals[co] = s;
        vals[4 + co] = q;
    }
    if (STORE) {
        int hy = (Y0 >> 1) + ty, hx = (X0 >> 1) + tx;
        if (hy < HP && hx < WP) {
#pragma unroll
            for (int co = 0; co < 4; co++) {
                float mx = fmaxf(fmaxf(acc[co][0][0], acc[co][0][1]),
                                 fmaxf(acc[co][1][0], acc[co][1][1]));
                float mn = fminf(fminf(acc[co][0][0], acc[co][0][1]),
                                 fminf(acc[co][1][0], acc[co][1][1]));
                size_t idx = (((size_t)b * 4 + co) * HP + hy) * WP + hx;
                pmax[idx] = mx;
                pmin[idx] = mn;
            }
        }
    }
    __syncthreads();
    float* red = (float*)h1t;
    rows_reduce<8>(red, vals, tid);
    int slot = ((b * 16) + blockIdx.y * 4 + blockIdx.x) & (NS - 1);
    if (tid < 8) atomicAdd(stats2 + slot * SLOT_STRIDE + tid, red[tid * 256]);
}

// ---------------- K3: BN2+relu on pooled extrema + spatial mean ----------------
__global__ void pool_bn_mean(const float* __restrict__ pmax, const float* __restrict__ pmin,
                             const float* __restrict__ g2, const float* __restrict__ be2,
                             const float* __restrict__ stats2,
                             float* __restrict__ featbuf, float N2) {
    __shared__ float red[256];
    int co = blockIdx.x & 3;
    int b = blockIdx.x >> 2;
    int tid = threadIdx.x;
    float su = slot_sum(stats2, co), sq = slot_sum(stats2, 4 + co);
    float mu = su / N2;
    float var = sq / N2 - mu * mu;
    float sc = g2[co] * rsqrtf(var + 1e-5f);
    float sh = be2[co] - mu * sc;
    const float* P = (sc >= 0.f ? pmax : pmin) + ((size_t)b * 4 + co) * (HP * WP);
    float s = 0.f;
    for (int i = tid; i < HP * WP; i += 256) s += fmaxf(fmaf(P[i], sc, sh), 0.f);
    red[tid] = s;
    __syncthreads();
    for (int st = 128; st > 0; st >>= 1) {
        if (tid < st) red[tid] += red[tid + st];
        __syncthreads();
    }
    if (tid == 0) featbuf[(size_t)b * 4 + co] = red[0];
}

// ---------------- K3c (tier C): conv2 recompute + BN2 + pool + spatial sum ----------------
__global__ void conv2_final_fused(const float* __restrict__ x, const float* __restrict__ w1,
                                  const float* __restrict__ b1, const float* __restrict__ g1,
                                  const float* __restrict__ be1,
                                  const float* __restrict__ stats1,
                                  const float* __restrict__ w2, const float* __restrict__ b2,
                                  const float* __restrict__ g2, const float* __restrict__ be2,
                                  const float* __restrict__ stats2,
                                  float* __restrict__ featbuf, float N1, float N2) {
    __shared__ __align__(16) float h1t[8][34][34];
    __shared__ float sc1[8], sh1[8];
    __shared__ float sc2[4], sh2[4];
    int b = blockIdx.z;
    int py0 = blockIdx.y * 16, px0 = blockIdx.x * 16;
    int ty = threadIdx.y, tx = threadIdx.x;
    int tid = ty * 16 + tx;
    if (tid < 8) {
        float su = slot_sum(stats1, tid), sq = slot_sum(stats1, 8 + tid);
        float mu = su / N1;
        float var = sq / N1 - mu * mu;
        float sc = g1[tid] * rsqrtf(var + 1e-5f);
        sc1[tid] = sc;
        sh1[tid] = be1[tid] - mu * sc;
    }
    if (tid >= 16 && tid < 20) {
        int j = tid - 16;
        float su = slot_sum(stats2, j), sq = slot_sum(stats2, 4 + j);
        float mu = su / N2;
        float var = sq / N2 - mu * mu;
        float sc = g2[j] * rsqrtf(var + 1e-5f);
        sc2[j] = sc;
        sh2[j] = be2[j] - mu * sc;
    }
    __syncthreads();
    const float* xb = x + (size_t)b * H1 * W1;
    build_h1_tile<34, 34>(xb, h1t, w1, b1, sc1, sh1, 2 * py0 - 1, 2 * px0 - 1, tid);
    __syncthreads();
    bool valid = (py0 + ty < HP) && (px0 + tx < WP);
    float acc[4][2][2];
#pragma unroll
    for (int co = 0; co < 4; co++)
#pragma unroll
        for (int dy = 0; dy < 2; dy++)
#pragma unroll
            for (int dx = 0; dx < 2; dx++) acc[co][dy][dx] = b2[co];
#pragma unroll
    for (int ci = 0; ci < 8; ci++) {
        float win[4][4];
#pragma unroll
        for (int r = 0; r < 4; r++) {
            const float2* rp = (const float2*)&h1t[ci][2 * ty + r][2 * tx];
            float2 u = rp[0], v = rp[1];
            win[r][0] = u.x; win[r][1] = u.y; win[r][2] = v.x; win[r][3] = v.y;
        }
#pragma unroll
        for (int co = 0; co < 4; co++)
#pragma unroll
            for (int ky = 0; ky < 3; ky++)
#pragma unroll
                for (int kx = 0; kx < 3; kx++) {
                    float wv = w2[co * 72 + ci * 9 + ky * 3 + kx];
#pragma unroll
                    for (int dy = 0; dy < 2; dy++)
#pragma unroll
                        for (int dx = 0; dx < 2; dx++)
                            acc[co][dy][dx] = fmaf(wv, win[dy + ky][dx + kx], acc[co][dy][dx]);
                }
    }
    float vals[4];
#pragma unroll
    for (int co = 0; co < 4; co++) {
        float mx = -INFINITY;
#pragma unroll
        for (int dy = 0; dy < 2; dy++)
#pragma unroll
            for (int dx = 0; dx < 2; dx++)
                mx = fmaxf(mx, fmaxf(fmaf(acc[co][dy][dx], sc2[co], sh2[co]), 0.f));
        vals[co] = valid ? mx : 0.f;
    }
    __syncthreads();
    float* red = (float*)h1t;
    rows_reduce<4>(red, vals, tid);
    if (tid < 4) atomicAdd(featbuf + (size_t)b * 4 + tid, red[tid * 256]);
}

// ---------------- K4: monolithic standardize + circuit + batch BN ----------------
__device__ __forceinline__ float bsum(float v, float* lds) {
#pragma unroll
    for (int off = 32; off; off >>= 1) v += __shfl_xor(v, off, 64);
    __syncthreads();
    if ((threadIdx.x & 63) == 0) lds[threadIdx.x >> 6] = v;
    __syncthreads();
    float r = 0.f;
    int nw = (int)(blockDim.x + 63) >> 6;
#pragma clang loop unroll(disable)
    for (int i = 0; i < nw; i++) r += lds[i];
    return r;
}

__global__ void finalize(const float* __restrict__ featbuf, const float* __restrict__ theta,
                         const float* __restrict__ rho, const float* __restrict__ ng,
                         const float* __restrict__ nb, float* __restrict__ out, int B) {
    __shared__ float lds[16];
    int b = threadIdx.x;
    float f[4];
#pragma unroll
    for (int j = 0; j < 4; j++) f[j] = featbuf[b * 4 + j] * (1.f / (HP * WP));
    float n = 4.f * (float)B;
    float mean = bsum(f[0] + f[1] + f[2] + f[3], lds) / n;
    float d2 = 0.f;
#pragma unroll
    for (int j = 0; j < 4; j++) { float d = f[j] - mean; d2 += d * d; }
    float var1 = bsum(d2, lds) / (n - 1.f);
    float stdv = sqrtf(fmaxf(var1, 0.f)) + 1e-6f;
    const float PI = 3.14159265358979323846f;
    float cs[4], sn[4];
#pragma unroll
    for (int j = 0; j < 4; j++) {
        float sc = (f[j] - mean) / stdv * PI;
        cs[j] = cosf(0.5f * sc);
        sn[j] = sinf(0.5f * sc);
    }
    C2 st[16];
    {
        float amp[16];
        amp[1] = sn[3]; amp[0] = cs[3];
#pragma unroll
        for (int k = 0; k < 2; k++) { amp[k + 2] = amp[k] * sn[2]; amp[k] *= cs[2]; }
#pragma unroll
        for (int k = 0; k < 4; k++) { amp[k + 4] = amp[k] * sn[1]; amp[k] *= cs[1]; }
#pragma unroll
        for (int k = 0; k < 8; k++) { amp[k + 8] = amp[k] * sn[0]; amp[k] *= cs[0]; }
#pragma unroll
        for (int i = 0; i < 16; i++) st[i] = C2{amp[i], 0.f};
    }
#pragma clang loop unroll(disable)
    for (int l = 0; l < 2; l++) {
        const float* p = (l == 0) ? theta : rho;
#pragma clang loop unroll(disable)
        for (int i = 0; i < 4; i++) {
            M2 U = combined_u(p + i * 3);
            switch (i) {
            case 0: ap1s<8>(st, U.m[0][0], U.m[0][1], U.m[1][0], U.m[1][1]); break;
            case 1: ap1s<4>(st, U.m[0][0], U.m[0][1], U.m[1][0], U.m[1][1]); break;
            case 2: ap1s<2>(st, U.m[0][0], U.m[0][1], U.m[1][0], U.m[1][1]); break;
            default: ap1s<1>(st, U.m[0][0], U.m[0][1], U.m[1][0], U.m[1][1]); break;
            }
        }
        if (l == 0) { cnot_s<8, 4>(st); cnot_s<4, 2>(st); cnot_s<2, 1>(st); }
        else        { cnot_s<4, 8>(st); cnot_s<2, 4>(st); cnot_s<1, 2>(st); }
    }
    float e[4];
#pragma unroll
    for (int qb = 0; qb < 4; qb++) {
        int m = 8 >> qb;
        float p0 = 0.f, p1 = 0.f;
#pragma unroll
        for (int i = 0; i < 16; i++) {
            float pr = st[i].re * st[i].re + st[i].im * st[i].im;
            if (i & m) p1 += pr; else p0 += pr;
        }
        e[qb] = p0 - p1;
    }
#pragma clang loop unroll(disable)
    for (int j = 0; j < 4; j++) {
        float mu = bsum(e[j], lds) / (float)B;
        float dv = e[j] - mu;
        float v = bsum(dv * dv, lds) / (float)B;
        out[b * 4 + j] = fmaf(dv, rsqrtf(v + 1e-5f) * ng[j], nb[j]);
    }
}

extern "C" void kernel_launch(void* const* d_in, const int* in_sizes, int n_in,
                              void* d_out, int out_size, void* d_ws, size_t ws_size,
                              hipStream_t stream) {
    const float* x     = (const float*)d_in[0];
    const float* w1    = (const float*)d_in[1];
    const float* b1    = (const float*)d_in[2];
    const float* g1    = (const float*)d_in[3];
    const float* be1   = (const float*)d_in[4];
    const float* w2    = (const float*)d_in[5];
    const float* b2    = (const float*)d_in[6];
    const float* g2    = (const float*)d_in[7];
    const float* be2   = (const float*)d_in[8];
    const float* theta = (const float*)d_in[9];
    const float* rho   = (const float*)d_in[10];
    const float* ng    = (const float*)d_in[11];
    const float* nb    = (const float*)d_in[12];
    float* out = (float*)d_out;

    int B = in_sizes[0] / (H1 * W1);

    float* ws = (float*)d_ws;
    float* stats1 = ws;                               // NS*64
    float* stats2 = ws + NS * SLOT_STRIDE;            // NS*64
    float* featbuf = ws + 2 * NS * SLOT_STRIDE;       // B*4
    float* bufs = featbuf + (size_t)B * 4;

    size_t common = (size_t)(2 * NS * SLOT_STRIDE) + (size_t)B * 4;
    size_t p2n = (size_t)B * 4 * HP * WP;             // pooled conv2 ext (one plane)
    size_t p1n = (size_t)B * 8 * H2 * W2;             // pooled conv1 ext, channel-last
    size_t needA = (common + p2n + p1n) * sizeof(float);
    size_t needB = (common + 2 * p2n) * sizeof(float);
    bool tierA = ws_size >= needA;                    // constant per process -> graph-safe
    bool tierB = !tierA && ws_size >= needB;

    float N1 = (float)B * H1 * W1;
    float N2 = (float)B * H2 * W2;
    int nz = (int)common;

    zero_ws<<<(nz + 255) / 256, 256, 0, stream>>>(ws, nz);
    if (tierA) {
        float* p2ext = bufs;
        float* p1ext = bufs + p2n;
        conv1_pool_stats<<<dim3(28, B), 256, 0, stream>>>(x, w1, b1, g1, stats1, p1ext);
        conv2_stats_slim<<<dim3(4, 4, B), dim3(16, 16), 0, stream>>>(
            p1ext, g1, be1, stats1, w2, b2, g2, stats2, p2ext, N1);
        pool_bn_mean<<<B * 4, 256, 0, stream>>>(p2ext, p2ext, g2, be2, stats2, featbuf, N2);
        finalize<<<1, B, 0, stream>>>(featbuf, theta, rho, ng, nb, out, B);
    } else if (tierB) {
        float* pmax = bufs;
        float* pmin = bufs + p2n;
        conv1_stats<<<dim3(28, B), 256, 0, stream>>>(x, w1, b1, stats1);
        conv2_stats_fused<true><<<dim3(4, 4, B), dim3(16, 16), 0, stream>>>(
            x, w1, b1, g1, be1, stats1, w2, b2, stats2, pmax, pmin, N1);
        pool_bn_mean<<<B * 4, 256, 0, stream>>>(pmax, pmin, g2, be2, stats2, featbuf, N2);
        finalize<<<1, B, 0, stream>>>(featbuf, theta, rho, ng, nb, out, B);
    } else {
        conv1_stats<<<dim3(28, B), 256, 0, stream>>>(x, w1, b1, stats1);
        conv2_stats_fused<false><<<dim3(4, 4, B), dim3(16, 16), 0, stream>>>(
            x, w1, b1, g1, be1, stats1, w2, b2, stats2, nullptr, nullptr, N1);
        conv2_final_fused<<<dim3(4, 4, B), dim3(16, 16), 0, stream>>>(
            x, w1, b1, g1, be1, stats1, w2, b2, g2, be2, stats2, featbuf, N1, N2);
        finalize<<<1, B, 0, stream>>>(featbuf, theta, rho, ng, nb, out, B);
    }
}